// Round 1
// baseline (2436.337 us; speedup 1.0000x reference)
//
#include <hip/hip_runtime.h>
#include <math.h>

constexpr int S_LEN = 2048;
constexpr int B_SZ  = 4;
constexpr int NROWS = B_SZ * S_LEN;   // 8192
constexpr float GAIN_  = 0.25f;
constexpr float EPS_   = 1e-6f;
constexpr float THETA_ = 10000.0f;
constexpr float SCALE_ = 0.17677669529663687f; // 1/sqrt(32)

__device__ __forceinline__ float block_reduce_sum_256(float v, float* scratch) {
    __syncthreads();  // protect scratch from previous use
    for (int off = 32; off > 0; off >>= 1)
        v += __shfl_down(v, off, 64);
    int lane = threadIdx.x & 63;
    int wid  = threadIdx.x >> 6;
    if (lane == 0) scratch[wid] = v;
    __syncthreads();
    if (threadIdx.x == 0) scratch[0] = scratch[0] + scratch[1] + scratch[2] + scratch[3];
    __syncthreads();
    return scratch[0];
}

// C[m][coloff+n] = sum_k A[m][k] * W[n][k]   (A: M x K, W: N x K, C row stride ldc)
__global__ __launch_bounds__(256) void gemm_awt(
    const float* __restrict__ A, const float* __restrict__ W,
    float* __restrict__ C, int Kdim, int ldc, int coloff) {
    __shared__ float As[64][17];
    __shared__ float Bs[64][17];
    int m0 = blockIdx.y * 64, n0 = blockIdx.x * 64;
    int tid = threadIdx.x;
    int tx = tid & 15, ty = tid >> 4;
    int lr = tid >> 2, lk = (tid & 3) * 4;
    float acc[4][4] = {};
    const float* Arow = A + (size_t)(m0 + lr) * Kdim + lk;
    const float* Wrow = W + (size_t)(n0 + lr) * Kdim + lk;
    for (int k0 = 0; k0 < Kdim; k0 += 16) {
        float4 av = *(const float4*)(Arow + k0);
        float4 bv = *(const float4*)(Wrow + k0);
        As[lr][lk + 0] = av.x; As[lr][lk + 1] = av.y;
        As[lr][lk + 2] = av.z; As[lr][lk + 3] = av.w;
        Bs[lr][lk + 0] = bv.x; Bs[lr][lk + 1] = bv.y;
        Bs[lr][lk + 2] = bv.z; Bs[lr][lk + 3] = bv.w;
        __syncthreads();
#pragma unroll
        for (int kk = 0; kk < 16; ++kk) {
            float a[4], b[4];
#pragma unroll
            for (int i = 0; i < 4; ++i) a[i] = As[ty * 4 + i][kk];
#pragma unroll
            for (int j = 0; j < 4; ++j) b[j] = Bs[tx * 4 + j][kk];
#pragma unroll
            for (int i = 0; i < 4; ++i)
#pragma unroll
                for (int j = 0; j < 4; ++j) acc[i][j] += a[i] * b[j];
        }
        __syncthreads();
    }
#pragma unroll
    for (int i = 0; i < 4; ++i) {
        float4 st = make_float4(acc[i][0], acc[i][1], acc[i][2], acc[i][3]);
        *(float4*)&C[(size_t)(m0 + ty * 4 + i) * ldc + coloff + n0 + tx * 4] = st;
    }
}

// RMS of q (512, g_latent), k (128, g_kv), v (128, g_kv) in place on qkv rows,
// plus head-means of post-RMS q (over 16 heads) and k (over 4 heads).
__global__ __launch_bounds__(256) void rms_qkv_means(
    float* __restrict__ qkv, const float* __restrict__ g_latent,
    const float* __restrict__ g_kv,
    float* __restrict__ qmean, float* __restrict__ kmean) {
    int row = blockIdx.x;
    float* p = qkv + (size_t)row * 768;
    __shared__ float sh[640];
    __shared__ float scratch[4];
    int tid = threadIdx.x;
    float v0 = p[tid], v1 = p[tid + 256], v2 = p[tid + 512];
    float ssq_q = block_reduce_sum_256(v0 * v0 + v1 * v1, scratch);
    float rq = rsqrtf(ssq_q / 512.f + EPS_);
    float q0 = v0 * rq * g_latent[tid];
    float q1 = v1 * rq * g_latent[tid + 256];
    p[tid] = q0; p[tid + 256] = q1;
    sh[tid] = q0; sh[tid + 256] = q1;
    float kpart = (tid < 128) ? v2 : 0.f;
    float vpart = (tid >= 128) ? v2 : 0.f;
    float ssq_k = block_reduce_sum_256(kpart * kpart, scratch);
    float ssq_v = block_reduce_sum_256(vpart * vpart, scratch);
    if (tid < 128) {
        float rk = rsqrtf(ssq_k / 128.f + EPS_);
        float kv = v2 * rk * g_kv[tid];
        p[512 + tid] = kv; sh[512 + tid] = kv;
    } else {
        float rv = rsqrtf(ssq_v / 128.f + EPS_);
        p[512 + tid] = v2 * rv * g_kv[tid - 128];
    }
    __syncthreads();
    if (tid < 32) {
        float s = 0.f;
#pragma unroll
        for (int h = 0; h < 16; ++h) s += sh[h * 32 + tid];
        qmean[(size_t)row * 32 + tid] = s * (1.f / 16.f);
    } else if (tid < 64) {
        int d = tid - 32;
        float s = 0.f;
#pragma unroll
        for (int h = 0; h < 4; ++h) s += sh[512 + h * 32 + d];
        kmean[(size_t)row * 32 + d] = s * 0.25f;
    }
}

// Grouped causal conv, 32 in / 32 out channels per group, K=3, left pad 2.
__global__ __launch_bounds__(256) void causal_conv32(
    const float* __restrict__ in, int ldin, int inoff,
    const float* __restrict__ w, float* __restrict__ out, int C) {
    int b = blockIdx.z, g = blockIdx.y, s0 = blockIdx.x * 32;
    __shared__ float wsh[32][3][32];   // [ic][tap][oc]
    __shared__ float ish[34][33];      // [pos][ic]
    int tid = threadIdx.x;
    for (int i = tid; i < 32 * 96; i += 256) {
        int oc = i / 96, r = i % 96;
        wsh[r / 3][r % 3][oc] = w[(size_t)(g * 32 + oc) * 96 + r];
    }
    for (int i = tid; i < 34 * 32; i += 256) {
        int pp = i >> 5, ic = i & 31;
        int s = s0 - 2 + pp;
        ish[pp][ic] = (s >= 0) ? in[((size_t)b * S_LEN + s) * ldin + inoff + g * 32 + ic] : 0.f;
    }
    __syncthreads();
    int sl = tid >> 3, oc0 = (tid & 7) * 4;
    float acc[4] = {0.f, 0.f, 0.f, 0.f};
    for (int ic = 0; ic < 32; ++ic) {
        float x0 = ish[sl][ic], x1 = ish[sl + 1][ic], x2 = ish[sl + 2][ic];
#pragma unroll
        for (int j = 0; j < 4; ++j)
            acc[j] += x0 * wsh[ic][0][oc0 + j] + x1 * wsh[ic][1][oc0 + j] + x2 * wsh[ic][2][oc0 + j];
    }
    float* orow = out + ((size_t)b * S_LEN + s0 + sl) * C + g * 32 + oc0;
    orow[0] = acc[0]; orow[1] = acc[1]; orow[2] = acc[2]; orow[3] = acc[3];
}

// Per-row: conv-RMS, + GAIN*mean-mix, post-RMS, per-head L2 norm (*sqrt(HD), k also
// *key_temp), RoPE. Writes final q (512) and k (128).
__global__ __launch_bounds__(256) void mix_rows(
    const float* __restrict__ convq, const float* __restrict__ convk,
    const float* __restrict__ qmean, const float* __restrict__ kmean,
    const float* __restrict__ g_conv, const float* __restrict__ g_kconv,
    const float* __restrict__ g_postq, const float* __restrict__ g_postk,
    const float* __restrict__ key_temp,
    float* __restrict__ qf, float* __restrict__ kf) {
    int row = blockIdx.x;
    int s = row & (S_LEN - 1);
    int tid = threadIdx.x;
    __shared__ float sh[640];
    __shared__ float scratch[4];
    __shared__ float hscale[20];
    float q0 = convq[(size_t)row * 512 + tid];
    float q1 = convq[(size_t)row * 512 + tid + 256];
    float k0 = (tid < 128) ? convk[(size_t)row * 128 + tid] : 0.f;
    float ssq = block_reduce_sum_256(q0 * q0 + q1 * q1, scratch);
    float r1 = rsqrtf(ssq / 512.f + EPS_);
    float ssk = block_reduce_sum_256(k0 * k0, scratch);
    float rk1 = rsqrtf(ssk / 128.f + EPS_);
    float km = kmean[(size_t)row * 32 + (tid & 31)];
    float a0 = q0 * r1 * g_conv[tid] + GAIN_ * km;
    float a1 = q1 * r1 * g_conv[tid + 256] + GAIN_ * km;
    float ak = 0.f;
    if (tid < 128) ak = k0 * rk1 * g_kconv[tid] + GAIN_ * qmean[(size_t)row * 32 + (tid & 31)];
    float ssq2 = block_reduce_sum_256(a0 * a0 + a1 * a1, scratch);
    float r2 = rsqrtf(ssq2 / 512.f + EPS_);
    float ssk2 = block_reduce_sum_256(ak * ak, scratch);
    float rk2 = rsqrtf(ssk2 / 128.f + EPS_);
    sh[tid] = a0 * r2 * g_postq[tid];
    sh[tid + 256] = a1 * r2 * g_postq[tid + 256];
    if (tid < 128) sh[512 + tid] = ak * rk2 * g_postk[tid];
    __syncthreads();
    if (tid < 16) {
        float ssh = 0.f;
        for (int d = 0; d < 32; ++d) { float x = sh[tid * 32 + d]; ssh += x * x; }
        hscale[tid] = sqrtf(32.f) / fmaxf(sqrtf(ssh), 1e-12f);
    } else if (tid < 20) {
        int h = tid - 16;
        float ssh = 0.f;
        for (int d = 0; d < 32; ++d) { float x = sh[512 + h * 32 + d]; ssh += x * x; }
        hscale[tid] = sqrtf(32.f) / fmaxf(sqrtf(ssh), 1e-12f) * key_temp[0];
    }
    __syncthreads();
    {   // q RoPE: 256 pairs
        int i0 = tid * 2;
        int h = i0 >> 5;
        int fi = (i0 & 31) >> 1;
        float sc = hscale[h];
        float x1 = sh[i0] * sc, x2 = sh[i0 + 1] * sc;
        float freq = powf(THETA_, -(float)fi / 16.f);
        float ang = (float)s * freq;
        float sn, cs;
        sincosf(ang, &sn, &cs);
        qf[(size_t)row * 512 + i0]     = x1 * cs - x2 * sn;
        qf[(size_t)row * 512 + i0 + 1] = x1 * sn + x2 * cs;
    }
    if (tid < 64) {  // k RoPE: 64 pairs
        int i0 = tid * 2;
        int h = i0 >> 5;
        int fi = (i0 & 31) >> 1;
        float sc = hscale[16 + h];
        float x1 = sh[512 + i0] * sc, x2 = sh[512 + i0 + 1] * sc;
        float freq = powf(THETA_, -(float)fi / 16.f);
        float ang = (float)s * freq;
        float sn, cs;
        sincosf(ang, &sn, &cs);
        kf[(size_t)row * 128 + i0]     = x1 * cs - x2 * sn;
        kf[(size_t)row * 128 + i0 + 1] = x1 * sn + x2 * cs;
    }
}

// Flash-style causal attention. Grid (32 qtiles, 16 heads, 4 batch), 256 threads.
__global__ __launch_bounds__(256) void attn_kernel(
    const float* __restrict__ qf, const float* __restrict__ kf,
    const float* __restrict__ vbuf /* qkv base, v at col 640, ld 768 */,
    float* __restrict__ obuf) {
    int qt = blockIdx.x, h = blockIdx.y, b = blockIdx.z;
    int kvh = h >> 2;
    __shared__ __align__(16) float Qs[64][36];
    __shared__ __align__(16) float Ks[64][36];
    __shared__ __align__(16) float Vs[64][36];
    __shared__ float Ps[64][65];
    __shared__ float mrow[64], lrow[64], arow[64];
    __shared__ float pm[64][4], psum[64][4];
    int tid = threadIdx.x;
    int qi = tid >> 2, qq = tid & 3;
    int dq = qq * 8;
    int s0 = qt * 64;
    {
        int r = tid >> 2, d0 = (tid & 3) * 8;
        const float* src = qf + ((size_t)b * S_LEN + s0 + r) * 512 + h * 32 + d0;
        float4 u0 = *(const float4*)src;
        float4 u1 = *(const float4*)(src + 4);
        Qs[r][d0 + 0] = u0.x; Qs[r][d0 + 1] = u0.y; Qs[r][d0 + 2] = u0.z; Qs[r][d0 + 3] = u0.w;
        Qs[r][d0 + 4] = u1.x; Qs[r][d0 + 5] = u1.y; Qs[r][d0 + 6] = u1.z; Qs[r][d0 + 7] = u1.w;
    }
    if (tid < 64) { mrow[tid] = -1e30f; lrow[tid] = 0.f; }
    __syncthreads();
    float qreg[32];
#pragma unroll
    for (int d = 0; d < 32; ++d) qreg[d] = Qs[qi][d];
    float O[8] = {0.f, 0.f, 0.f, 0.f, 0.f, 0.f, 0.f, 0.f};
    int qpos = s0 + qi;
    for (int kt = 0; kt <= qt; ++kt) {
        __syncthreads();  // previous PV done before overwriting Ks/Vs
        {
            int r = tid >> 2, d0 = (tid & 3) * 8;
            int ks = kt * 64 + r;
            const float* ksrc = kf + ((size_t)b * S_LEN + ks) * 128 + kvh * 32 + d0;
            float4 u0 = *(const float4*)ksrc;
            float4 u1 = *(const float4*)(ksrc + 4);
            Ks[r][d0 + 0] = u0.x; Ks[r][d0 + 1] = u0.y; Ks[r][d0 + 2] = u0.z; Ks[r][d0 + 3] = u0.w;
            Ks[r][d0 + 4] = u1.x; Ks[r][d0 + 5] = u1.y; Ks[r][d0 + 6] = u1.z; Ks[r][d0 + 7] = u1.w;
            const float* vsrc = vbuf + ((size_t)b * S_LEN + ks) * 768 + 640 + kvh * 32 + d0;
            float4 w0 = *(const float4*)vsrc;
            float4 w1 = *(const float4*)(vsrc + 4);
            Vs[r][d0 + 0] = w0.x; Vs[r][d0 + 1] = w0.y; Vs[r][d0 + 2] = w0.z; Vs[r][d0 + 3] = w0.w;
            Vs[r][d0 + 4] = w1.x; Vs[r][d0 + 5] = w1.y; Vs[r][d0 + 6] = w1.z; Vs[r][d0 + 7] = w1.w;
        }
        __syncthreads();
        float sc[16];
        float lmax = -1e30f;
#pragma unroll
        for (int jj = 0; jj < 16; ++jj) {
            int kj = qq * 16 + jj;
            int kpos = kt * 64 + kj;
            float dotv = 0.f;
#pragma unroll
            for (int d4 = 0; d4 < 32; d4 += 4) {
                float4 kv4 = *(const float4*)&Ks[kj][d4];
                dotv += qreg[d4 + 0] * kv4.x + qreg[d4 + 1] * kv4.y +
                        qreg[d4 + 2] * kv4.z + qreg[d4 + 3] * kv4.w;
            }
            float sval = (kpos <= qpos) ? dotv * SCALE_ : -1e30f;
            sc[jj] = sval;
            lmax = fmaxf(lmax, sval);
        }
        pm[qi][qq] = lmax;
        __syncthreads();
        if (qq == 0) {
            float mnew = fmaxf(fmaxf(fmaxf(pm[qi][0], pm[qi][1]), fmaxf(pm[qi][2], pm[qi][3])), mrow[qi]);
            arow[qi] = __expf(mrow[qi] - mnew);
            mrow[qi] = mnew;
        }
        __syncthreads();
        float mnew = mrow[qi];
        float alpha = arow[qi];
#pragma unroll
        for (int j = 0; j < 8; ++j) O[j] *= alpha;
        float lsum = 0.f;
#pragma unroll
        for (int jj = 0; jj < 16; ++jj) {
            float pv = __expf(sc[jj] - mnew);
            Ps[qi][qq * 16 + jj] = pv;
            lsum += pv;
        }
        psum[qi][qq] = lsum;
        __syncthreads();
        if (qq == 0)
            lrow[qi] = lrow[qi] * alpha + psum[qi][0] + psum[qi][1] + psum[qi][2] + psum[qi][3];
#pragma unroll 4
        for (int kj = 0; kj < 64; ++kj) {
            float pv = Ps[qi][kj];
            float4 v0 = *(const float4*)&Vs[kj][dq];
            float4 v1 = *(const float4*)&Vs[kj][dq + 4];
            O[0] += pv * v0.x; O[1] += pv * v0.y; O[2] += pv * v0.z; O[3] += pv * v0.w;
            O[4] += pv * v1.x; O[5] += pv * v1.y; O[6] += pv * v1.z; O[7] += pv * v1.w;
        }
    }
    __syncthreads();
    float linv = 1.f / lrow[qi];
    float* dst = obuf + ((size_t)b * S_LEN + s0 + qi) * 512 + h * 32 + dq;
    float4 o0 = make_float4(O[0] * linv, O[1] * linv, O[2] * linv, O[3] * linv);
    float4 o1 = make_float4(O[4] * linv, O[5] * linv, O[6] * linv, O[7] * linv);
    *(float4*)dst = o0;
    *(float4*)(dst + 4) = o1;
}

__global__ __launch_bounds__(256) void rms_preout(
    float* __restrict__ buf, const float* __restrict__ g) {
    int row = blockIdx.x;
    float* p = buf + (size_t)row * 512;
    __shared__ float scratch[4];
    int tid = threadIdx.x;
    float v0 = p[tid], v1 = p[tid + 256];
    float ssq = block_reduce_sum_256(v0 * v0 + v1 * v1, scratch);
    float r = rsqrtf(ssq / 512.f + EPS_);
    p[tid] = v0 * r * g[tid];
    p[tid + 256] = v1 * r * g[tid + 256];
}

extern "C" void kernel_launch(void* const* d_in, const int* in_sizes, int n_in,
                              void* d_out, int out_size, void* d_ws, size_t ws_size,
                              hipStream_t stream) {
    (void)in_sizes; (void)n_in; (void)out_size; (void)ws_size;
    const float* x        = (const float*)d_in[0];
    const float* w_q      = (const float*)d_in[1];
    const float* w_k      = (const float*)d_in[2];
    const float* w_v      = (const float*)d_in[3];
    const float* g_latent = (const float*)d_in[4];
    const float* g_kv     = (const float*)d_in[5];
    const float* conv_q_w = (const float*)d_in[6];
    const float* conv_k_w = (const float*)d_in[7];
    const float* g_conv   = (const float*)d_in[8];
    const float* g_kconv  = (const float*)d_in[9];
    const float* g_postq  = (const float*)d_in[10];
    const float* g_postk  = (const float*)d_in[11];
    const float* key_temp = (const float*)d_in[12];
    const float* g_preout = (const float*)d_in[13];
    const float* w_o      = (const float*)d_in[14];
    float* out = (float*)d_out;

    float* ws = (float*)d_ws;
    const size_t R = NROWS;
    float* qkv   = ws;                  // R*768  (q | k | v) post-RMS
    float* qmean = qkv + R * 768;       // R*32
    float* kmean = qmean + R * 32;      // R*32
    float* convq = kmean + R * 32;      // R*512  (reused as attention output)
    float* convk = convq + R * 512;     // R*128
    float* qfin  = convk + R * 128;     // R*512
    float* kfin  = qfin + R * 512;      // R*128
    float* attn  = convq;               // reuse: convq consumed by mix_rows before attn

    dim3 blk(256);
    gemm_awt<<<dim3(8, 128), blk, 0, stream>>>(x, w_q, qkv, 2048, 768, 0);
    gemm_awt<<<dim3(2, 128), blk, 0, stream>>>(x, w_k, qkv, 2048, 768, 512);
    gemm_awt<<<dim3(2, 128), blk, 0, stream>>>(x, w_v, qkv, 2048, 768, 640);
    rms_qkv_means<<<NROWS, blk, 0, stream>>>(qkv, g_latent, g_kv, qmean, kmean);
    causal_conv32<<<dim3(64, 16, 4), blk, 0, stream>>>(qkv, 768, 0, conv_q_w, convq, 512);
    causal_conv32<<<dim3(64, 4, 4), blk, 0, stream>>>(qkv, 768, 512, conv_k_w, convk, 128);
    mix_rows<<<NROWS, blk, 0, stream>>>(convq, convk, qmean, kmean, g_conv, g_kconv,
                                        g_postq, g_postk, key_temp, qfin, kfin);
    attn_kernel<<<dim3(32, 16, 4), blk, 0, stream>>>(qfin, kfin, qkv, attn);
    rms_preout<<<NROWS, blk, 0, stream>>>(attn, g_preout);
    gemm_awt<<<dim3(32, 128), blk, 0, stream>>>(attn, w_o, out, 512, 2048, 0);
}

// Round 2
// 1368.340 us; speedup vs baseline: 1.7805x; 1.7805x over previous
//
#include <hip/hip_runtime.h>
#include <hip/hip_bf16.h>
#include <math.h>

constexpr int S_LEN = 2048;
constexpr int B_SZ  = 4;
constexpr int NROWS = B_SZ * S_LEN;   // 8192
constexpr float GAIN_  = 0.25f;
constexpr float EPS_   = 1e-6f;
constexpr float THETA_ = 10000.0f;
constexpr float SCALE_ = 0.17677669529663687f; // 1/sqrt(32)

typedef __attribute__((ext_vector_type(8))) short short8;
typedef __attribute__((ext_vector_type(4))) float float4v;

__device__ __forceinline__ short f2bs(float f) {
    __hip_bfloat16 h = __float2bfloat16(f);
    short r;
    __builtin_memcpy(&r, &h, 2);
    return r;
}

__device__ __forceinline__ float block_reduce_sum_256(float v, float* scratch) {
    __syncthreads();  // protect scratch from previous use
    for (int off = 32; off > 0; off >>= 1)
        v += __shfl_down(v, off, 64);
    int lane = threadIdx.x & 63;
    int wid  = threadIdx.x >> 6;
    if (lane == 0) scratch[wid] = v;
    __syncthreads();
    if (threadIdx.x == 0) scratch[0] = scratch[0] + scratch[1] + scratch[2] + scratch[3];
    __syncthreads();
    return scratch[0];
}

// C[m][coloff+n] = sum_k A[m][k] * W[n][k]   (A: M x K, W: N x K, C row stride ldc)
__global__ __launch_bounds__(256) void gemm_awt(
    const float* __restrict__ A, const float* __restrict__ W,
    float* __restrict__ C, int Kdim, int ldc, int coloff) {
    __shared__ float As[64][17];
    __shared__ float Bs[64][17];
    int m0 = blockIdx.y * 64, n0 = blockIdx.x * 64;
    int tid = threadIdx.x;
    int tx = tid & 15, ty = tid >> 4;
    int lr = tid >> 2, lk = (tid & 3) * 4;
    float acc[4][4] = {};
    const float* Arow = A + (size_t)(m0 + lr) * Kdim + lk;
    const float* Wrow = W + (size_t)(n0 + lr) * Kdim + lk;
    for (int k0 = 0; k0 < Kdim; k0 += 16) {
        float4 av = *(const float4*)(Arow + k0);
        float4 bv = *(const float4*)(Wrow + k0);
        As[lr][lk + 0] = av.x; As[lr][lk + 1] = av.y;
        As[lr][lk + 2] = av.z; As[lr][lk + 3] = av.w;
        Bs[lr][lk + 0] = bv.x; Bs[lr][lk + 1] = bv.y;
        Bs[lr][lk + 2] = bv.z; Bs[lr][lk + 3] = bv.w;
        __syncthreads();
#pragma unroll
        for (int kk = 0; kk < 16; ++kk) {
            float a[4], b[4];
#pragma unroll
            for (int i = 0; i < 4; ++i) a[i] = As[ty * 4 + i][kk];
#pragma unroll
            for (int j = 0; j < 4; ++j) b[j] = Bs[tx * 4 + j][kk];
#pragma unroll
            for (int i = 0; i < 4; ++i)
#pragma unroll
                for (int j = 0; j < 4; ++j) acc[i][j] += a[i] * b[j];
        }
        __syncthreads();
    }
#pragma unroll
    for (int i = 0; i < 4; ++i) {
        float4 st = make_float4(acc[i][0], acc[i][1], acc[i][2], acc[i][3]);
        *(float4*)&C[(size_t)(m0 + ty * 4 + i) * ldc + coloff + n0 + tx * 4] = st;
    }
}

// RMS of q (512, g_latent), k (128, g_kv), v (128, g_kv); q,k stored back to qkv,
// v stored as bf16 transposed vtb[(b*4+kvh)*32+d][s]. Also head-means of q and k.
__global__ __launch_bounds__(256) void rms_qkv_means(
    float* __restrict__ qkv, const float* __restrict__ g_latent,
    const float* __restrict__ g_kv,
    float* __restrict__ qmean, float* __restrict__ kmean,
    short* __restrict__ vtb) {
    int row = blockIdx.x;
    int b = row >> 11, s = row & (S_LEN - 1);
    float* p = qkv + (size_t)row * 768;
    __shared__ float sh[640];
    __shared__ float scratch[4];
    int tid = threadIdx.x;
    float v0 = p[tid], v1 = p[tid + 256], v2 = p[tid + 512];
    float ssq_q = block_reduce_sum_256(v0 * v0 + v1 * v1, scratch);
    float rq = rsqrtf(ssq_q / 512.f + EPS_);
    float q0 = v0 * rq * g_latent[tid];
    float q1 = v1 * rq * g_latent[tid + 256];
    p[tid] = q0; p[tid + 256] = q1;
    sh[tid] = q0; sh[tid + 256] = q1;
    float kpart = (tid < 128) ? v2 : 0.f;
    float vpart = (tid >= 128) ? v2 : 0.f;
    float ssq_k = block_reduce_sum_256(kpart * kpart, scratch);
    float ssq_v = block_reduce_sum_256(vpart * vpart, scratch);
    if (tid < 128) {
        float rk = rsqrtf(ssq_k / 128.f + EPS_);
        float kv = v2 * rk * g_kv[tid];
        p[512 + tid] = kv; sh[512 + tid] = kv;
    } else {
        float rv = rsqrtf(ssq_v / 128.f + EPS_);
        float vv = v2 * rv * g_kv[tid - 128];
        int d_full = tid - 128;
        vtb[((size_t)(b * 4 + (d_full >> 5)) * 32 + (d_full & 31)) * S_LEN + s] = f2bs(vv);
    }
    __syncthreads();
    if (tid < 32) {
        float sm = 0.f;
#pragma unroll
        for (int h = 0; h < 16; ++h) sm += sh[h * 32 + tid];
        qmean[(size_t)row * 32 + tid] = sm * (1.f / 16.f);
    } else if (tid < 64) {
        int d = tid - 32;
        float sm = 0.f;
#pragma unroll
        for (int h = 0; h < 4; ++h) sm += sh[512 + h * 32 + d];
        kmean[(size_t)row * 32 + d] = sm * 0.25f;
    }
}

// Grouped causal conv, 32 in / 32 out channels per group, K=3, left pad 2.
__global__ __launch_bounds__(256) void causal_conv32(
    const float* __restrict__ in, int ldin, int inoff,
    const float* __restrict__ w, float* __restrict__ out, int C) {
    int b = blockIdx.z, g = blockIdx.y, s0 = blockIdx.x * 32;
    __shared__ float wsh[32][3][32];   // [ic][tap][oc]
    __shared__ float ish[34][33];      // [pos][ic]
    int tid = threadIdx.x;
    for (int i = tid; i < 32 * 96; i += 256) {
        int oc = i / 96, r = i % 96;
        wsh[r / 3][r % 3][oc] = w[(size_t)(g * 32 + oc) * 96 + r];
    }
    for (int i = tid; i < 34 * 32; i += 256) {
        int pp = i >> 5, ic = i & 31;
        int s = s0 - 2 + pp;
        ish[pp][ic] = (s >= 0) ? in[((size_t)b * S_LEN + s) * ldin + inoff + g * 32 + ic] : 0.f;
    }
    __syncthreads();
    int sl = tid >> 3, oc0 = (tid & 7) * 4;
    float acc[4] = {0.f, 0.f, 0.f, 0.f};
    for (int ic = 0; ic < 32; ++ic) {
        float x0 = ish[sl][ic], x1 = ish[sl + 1][ic], x2 = ish[sl + 2][ic];
#pragma unroll
        for (int j = 0; j < 4; ++j)
            acc[j] += x0 * wsh[ic][0][oc0 + j] + x1 * wsh[ic][1][oc0 + j] + x2 * wsh[ic][2][oc0 + j];
    }
    float* orow = out + ((size_t)b * S_LEN + s0 + sl) * C + g * 32 + oc0;
    orow[0] = acc[0]; orow[1] = acc[1]; orow[2] = acc[2]; orow[3] = acc[3];
}

// Per-row: conv-RMS, + GAIN*mean-mix, post-RMS, per-head L2 norm, RoPE.
// Writes final q (512) and k (128) as bf16.
__global__ __launch_bounds__(256) void mix_rows(
    const float* __restrict__ convq, const float* __restrict__ convk,
    const float* __restrict__ qmean, const float* __restrict__ kmean,
    const float* __restrict__ g_conv, const float* __restrict__ g_kconv,
    const float* __restrict__ g_postq, const float* __restrict__ g_postk,
    const float* __restrict__ key_temp,
    short* __restrict__ qb, short* __restrict__ kb) {
    int row = blockIdx.x;
    int s = row & (S_LEN - 1);
    int tid = threadIdx.x;
    __shared__ float sh[640];
    __shared__ float scratch[4];
    __shared__ float hscale[20];
    float q0 = convq[(size_t)row * 512 + tid];
    float q1 = convq[(size_t)row * 512 + tid + 256];
    float k0 = (tid < 128) ? convk[(size_t)row * 128 + tid] : 0.f;
    float ssq = block_reduce_sum_256(q0 * q0 + q1 * q1, scratch);
    float r1 = rsqrtf(ssq / 512.f + EPS_);
    float ssk = block_reduce_sum_256(k0 * k0, scratch);
    float rk1 = rsqrtf(ssk / 128.f + EPS_);
    float km = kmean[(size_t)row * 32 + (tid & 31)];
    float a0 = q0 * r1 * g_conv[tid] + GAIN_ * km;
    float a1 = q1 * r1 * g_conv[tid + 256] + GAIN_ * km;
    float ak = 0.f;
    if (tid < 128) ak = k0 * rk1 * g_kconv[tid] + GAIN_ * qmean[(size_t)row * 32 + (tid & 31)];
    float ssq2 = block_reduce_sum_256(a0 * a0 + a1 * a1, scratch);
    float r2 = rsqrtf(ssq2 / 512.f + EPS_);
    float ssk2 = block_reduce_sum_256(ak * ak, scratch);
    float rk2 = rsqrtf(ssk2 / 128.f + EPS_);
    sh[tid] = a0 * r2 * g_postq[tid];
    sh[tid + 256] = a1 * r2 * g_postq[tid + 256];
    if (tid < 128) sh[512 + tid] = ak * rk2 * g_postk[tid];
    __syncthreads();
    if (tid < 16) {
        float ssh = 0.f;
        for (int d = 0; d < 32; ++d) { float x = sh[tid * 32 + d]; ssh += x * x; }
        hscale[tid] = sqrtf(32.f) / fmaxf(sqrtf(ssh), 1e-12f);
    } else if (tid < 20) {
        int h = tid - 16;
        float ssh = 0.f;
        for (int d = 0; d < 32; ++d) { float x = sh[512 + h * 32 + d]; ssh += x * x; }
        hscale[tid] = sqrtf(32.f) / fmaxf(sqrtf(ssh), 1e-12f) * key_temp[0];
    }
    __syncthreads();
    {   // q RoPE: 256 pairs
        int i0 = tid * 2;
        int h = i0 >> 5;
        int fi = (i0 & 31) >> 1;
        float sc = hscale[h];
        float x1 = sh[i0] * sc, x2 = sh[i0 + 1] * sc;
        float freq = powf(THETA_, -(float)fi / 16.f);
        float ang = (float)s * freq;
        float sn, cs;
        sincosf(ang, &sn, &cs);
        qb[(size_t)row * 512 + i0]     = f2bs(x1 * cs - x2 * sn);
        qb[(size_t)row * 512 + i0 + 1] = f2bs(x1 * sn + x2 * cs);
    }
    if (tid < 64) {  // k RoPE: 64 pairs
        int i0 = tid * 2;
        int h = i0 >> 5;
        int fi = (i0 & 31) >> 1;
        float sc = hscale[16 + h];
        float x1 = sh[512 + i0] * sc, x2 = sh[512 + i0 + 1] * sc;
        float freq = powf(THETA_, -(float)fi / 16.f);
        float ang = (float)s * freq;
        float sn, cs;
        sincosf(ang, &sn, &cs);
        kb[(size_t)row * 128 + i0]     = f2bs(x1 * cs - x2 * sn);
        kb[(size_t)row * 128 + i0 + 1] = f2bs(x1 * sn + x2 * cs);
    }
}

// MFMA flash attention. Grid (32 qtiles, 16 heads, 4 batch), 256 threads = 4 waves.
// Each wave owns 16 q-rows. K/V staged in LDS in frag order (lane-contiguous b128).
__global__ __launch_bounds__(256) void attn_mfma(
    const short* __restrict__ qb, const short* __restrict__ kb,
    const short* __restrict__ vtb, float* __restrict__ obuf) {
    int qt = blockIdx.x, h = blockIdx.y, b = blockIdx.z;
    int kvh = h >> 2;
    int s0 = qt * 64;
    __shared__ short KF[2048];   // [chunk][quad][c][j]  4KB
    __shared__ short VF[2048];   // [kc][dc][quad][c][j]  4KB
    __shared__ short PF[4096];   // per wave 1024: [kc][quad][c][j]  8KB
    int tid = threadIdx.x;
    int wave = tid >> 6, lane = tid & 63;
    int qc = lane >> 4, cc = lane & 15;

    // Q A-frag straight from global: A[m=cc][k=8*qc+j]
    short8 qfrag = *(const short8*)(qb +
        ((size_t)(b * S_LEN + s0 + wave * 16 + cc) * 512 + h * 32 + qc * 8));

    float4v accO[2];
    accO[0] = (float4v){0.f, 0.f, 0.f, 0.f};
    accO[1] = (float4v){0.f, 0.f, 0.f, 0.f};
    float mrow[4] = {-1e30f, -1e30f, -1e30f, -1e30f};
    float lrow[4] = {0.f, 0.f, 0.f, 0.f};
    int qpos_base = s0 + wave * 16 + qc * 4;

    for (int kt = 0; kt <= qt; ++kt) {
        __syncthreads();
        {   // stage K frags: KF elem (chunk=t>>6, quad=(t>>4)&3, c=t&15)
            int chunk = tid >> 6, quad = (tid >> 4) & 3, c = tid & 15;
            const short* src = kb +
                ((size_t)(b * S_LEN + kt * 64 + chunk * 16 + c) * 128 + kvh * 32 + quad * 8);
            *(short8*)&KF[tid * 8] = *(const short8*)src;
            // stage V frags: VF elem (kc=t>>7, dc=(t>>6)&1, quad, c)
            int kc = tid >> 7, dc = (tid >> 6) & 1;
            const short* vsrc = vtb +
                ((size_t)((b * 4 + kvh) * 32 + dc * 16 + c) * S_LEN + kt * 64 + kc * 32 + quad * 8);
            *(short8*)&VF[tid * 8] = *(const short8*)vsrc;
        }
        __syncthreads();

        // QK^T: 4 MFMAs over k-position chunks of 16
        float4v sc[4];
#pragma unroll
        for (int chunk = 0; chunk < 4; ++chunk) {
            short8 kfrag = *(const short8*)&KF[chunk * 512 + lane * 8];
            float4v z = (float4v){0.f, 0.f, 0.f, 0.f};
            sc[chunk] = __builtin_amdgcn_mfma_f32_16x16x32_bf16(qfrag, kfrag, z, 0, 0, 0);
        }

        // scale + causal mask; per-row online softmax (rows r=0..3, row=qc*4+r)
#pragma unroll
        for (int r = 0; r < 4; ++r) {
            int qpos = qpos_base + r;
            float sv[4];
            float lm = -1e30f;
#pragma unroll
            for (int chunk = 0; chunk < 4; ++chunk) {
                int kpos = kt * 64 + chunk * 16 + cc;
                float v = sc[chunk][r] * SCALE_;
                v = (kpos <= qpos) ? v : -1e30f;
                sv[chunk] = v;
                lm = fmaxf(lm, v);
            }
#pragma unroll
            for (int mask = 1; mask < 16; mask <<= 1)
                lm = fmaxf(lm, __shfl_xor(lm, mask, 64));
            float mnew = fmaxf(mrow[r], lm);
            float alpha = __expf(mrow[r] - mnew);
            mrow[r] = mnew;
            accO[0][r] *= alpha;
            accO[1][r] *= alpha;
            float lsum = 0.f;
            int m_idx = qc * 4 + r;
#pragma unroll
            for (int chunk = 0; chunk < 4; ++chunk) {
                float pv = __expf(sv[chunk] - mnew);
                lsum += pv;
                int k = chunk * 16 + cc;
                PF[wave * 1024 + (k >> 5) * 512 + (((k >> 3) & 3) * 16 + m_idx) * 8 + (k & 7)]
                    = f2bs(pv);
            }
#pragma unroll
            for (int mask = 1; mask < 16; mask <<= 1)
                lsum += __shfl_xor(lsum, mask, 64);
            lrow[r] = lrow[r] * alpha + lsum;
        }

        // PV: O[q][d] += P · V  (2 k-chunks × 2 d-chunks)
#pragma unroll
        for (int kc = 0; kc < 2; ++kc) {
            short8 pfrag = *(const short8*)&PF[wave * 1024 + kc * 512 + lane * 8];
#pragma unroll
            for (int dc = 0; dc < 2; ++dc) {
                short8 vfrag = *(const short8*)&VF[(kc * 2 + dc) * 512 + lane * 8];
                accO[dc] = __builtin_amdgcn_mfma_f32_16x16x32_bf16(pfrag, vfrag, accO[dc], 0, 0, 0);
            }
        }
    }

    // epilogue: normalize by l, write fp32
#pragma unroll
    for (int r = 0; r < 4; ++r) {
        float linv = 1.f / lrow[r];
        float* dst = obuf + ((size_t)(b * S_LEN + s0 + wave * 16 + qc * 4 + r) * 512 + h * 32 + cc);
        dst[0]  = accO[0][r] * linv;
        dst[16] = accO[1][r] * linv;
    }
}

__global__ __launch_bounds__(256) void rms_preout(
    float* __restrict__ buf, const float* __restrict__ g) {
    int row = blockIdx.x;
    float* p = buf + (size_t)row * 512;
    __shared__ float scratch[4];
    int tid = threadIdx.x;
    float v0 = p[tid], v1 = p[tid + 256];
    float ssq = block_reduce_sum_256(v0 * v0 + v1 * v1, scratch);
    float r = rsqrtf(ssq / 512.f + EPS_);
    p[tid] = v0 * r * g[tid];
    p[tid + 256] = v1 * r * g[tid + 256];
}

extern "C" void kernel_launch(void* const* d_in, const int* in_sizes, int n_in,
                              void* d_out, int out_size, void* d_ws, size_t ws_size,
                              hipStream_t stream) {
    (void)in_sizes; (void)n_in; (void)out_size; (void)ws_size;
    const float* x        = (const float*)d_in[0];
    const float* w_q      = (const float*)d_in[1];
    const float* w_k      = (const float*)d_in[2];
    const float* w_v      = (const float*)d_in[3];
    const float* g_latent = (const float*)d_in[4];
    const float* g_kv     = (const float*)d_in[5];
    const float* conv_q_w = (const float*)d_in[6];
    const float* conv_k_w = (const float*)d_in[7];
    const float* g_conv   = (const float*)d_in[8];
    const float* g_kconv  = (const float*)d_in[9];
    const float* g_postq  = (const float*)d_in[10];
    const float* g_postk  = (const float*)d_in[11];
    const float* key_temp = (const float*)d_in[12];
    const float* g_preout = (const float*)d_in[13];
    const float* w_o      = (const float*)d_in[14];
    float* out = (float*)d_out;

    char* ws = (char*)d_ws;
    const size_t R = NROWS;
    float* qkv   = (float*)ws;                        ws += R * 768 * 4;
    float* qmean = (float*)ws;                        ws += R * 32 * 4;
    float* kmean = (float*)ws;                        ws += R * 32 * 4;
    float* convq = (float*)ws;                        ws += R * 512 * 4;
    float* convk = (float*)ws;                        ws += R * 128 * 4;
    short* qbb   = (short*)ws;                        ws += R * 512 * 2;
    short* kbb   = (short*)ws;                        ws += R * 128 * 2;
    short* vtb   = (short*)ws;                        ws += R * 128 * 2;
    float* attn  = convq;  // convq consumed by mix_rows before attn writes

    dim3 blk(256);
    gemm_awt<<<dim3(8, 128), blk, 0, stream>>>(x, w_q, qkv, 2048, 768, 0);
    gemm_awt<<<dim3(2, 128), blk, 0, stream>>>(x, w_k, qkv, 2048, 768, 512);
    gemm_awt<<<dim3(2, 128), blk, 0, stream>>>(x, w_v, qkv, 2048, 768, 640);
    rms_qkv_means<<<NROWS, blk, 0, stream>>>(qkv, g_latent, g_kv, qmean, kmean, vtb);
    causal_conv32<<<dim3(64, 16, 4), blk, 0, stream>>>(qkv, 768, 0, conv_q_w, convq, 512);
    causal_conv32<<<dim3(64, 4, 4), blk, 0, stream>>>(qkv, 768, 512, conv_k_w, convk, 128);
    mix_rows<<<NROWS, blk, 0, stream>>>(convq, convk, qmean, kmean, g_conv, g_kconv,
                                        g_postq, g_postk, key_temp, qbb, kbb);
    attn_mfma<<<dim3(32, 16, 4), blk, 0, stream>>>(qbb, kbb, vtb, attn);
    rms_preout<<<NROWS, blk, 0, stream>>>(attn, g_preout);
    gemm_awt<<<dim3(32, 128), blk, 0, stream>>>(attn, w_o, out, 512, 2048, 0);
}

// Round 3
// 509.381 us; speedup vs baseline: 4.7829x; 2.6863x over previous
//
#include <hip/hip_runtime.h>
#include <hip/hip_bf16.h>
#include <math.h>

constexpr int S_LEN = 2048;
constexpr int B_SZ  = 4;
constexpr int NROWS = B_SZ * S_LEN;   // 8192
constexpr float GAIN_  = 0.25f;
constexpr float EPS_   = 1e-6f;
constexpr float THETA_ = 10000.0f;
constexpr float SCALE_ = 0.17677669529663687f; // 1/sqrt(32)

typedef __attribute__((ext_vector_type(8))) short short8;
typedef __attribute__((ext_vector_type(4))) float float4v;

__device__ __forceinline__ short f2bs(float f) {
    __hip_bfloat16 h = __float2bfloat16(f);
    short r;
    __builtin_memcpy(&r, &h, 2);
    return r;
}

__device__ __forceinline__ void async_copy16(const short* g, short* l) {
    __builtin_amdgcn_global_load_lds(
        (const __attribute__((address_space(1))) void*)g,
        (__attribute__((address_space(3))) void*)l, 16, 0, 0);
}

__device__ __forceinline__ float block_reduce_sum_256(float v, float* scratch) {
    __syncthreads();
    for (int off = 32; off > 0; off >>= 1)
        v += __shfl_down(v, off, 64);
    int lane = threadIdx.x & 63;
    int wid  = threadIdx.x >> 6;
    if (lane == 0) scratch[wid] = v;
    __syncthreads();
    if (threadIdx.x == 0) scratch[0] = scratch[0] + scratch[1] + scratch[2] + scratch[3];
    __syncthreads();
    return scratch[0];
}

// fp32 -> bf16 cast, n % 4 == 0
__global__ __launch_bounds__(256) void cvt_bf16(
    const float* __restrict__ src, short* __restrict__ dst, int n) {
    int i = (blockIdx.x * 256 + threadIdx.x) * 4;
    if (i >= n) return;
    float4 v = *(const float4*)(src + i);
    dst[i + 0] = f2bs(v.x); dst[i + 1] = f2bs(v.y);
    dst[i + 2] = f2bs(v.z); dst[i + 3] = f2bs(v.w);
}

// C[M x N] fp32 = A[M x K](bf16) @ B[N x K](bf16)^T.  M%128==0, N%128==0, K%32==0.
// 128x128 tile, 4 waves each 64x64 via 16x16x32 MFMA, global_load_lds staging.
__global__ __launch_bounds__(256) void gemm_bf16_mfma(
    const short* __restrict__ A, const short* __restrict__ B,
    float* __restrict__ C, int N, int K) {
    __shared__ short As[128 * 32];
    __shared__ short Bs[128 * 32];
    int tid = threadIdx.x;
    int wave = tid >> 6, lane = tid & 63;
    int m0 = blockIdx.y * 128, n0 = blockIdx.x * 128;
    int wm = (wave >> 1) * 64, wn = (wave & 1) * 64;
    int mrow = lane & 15, quad = lane >> 4;
    float4v acc[4][4] = {};
    for (int k0 = 0; k0 < K; k0 += 32) {
        __syncthreads();
#pragma unroll
        for (int p = 0; p < 2; ++p) {
            int f = p * 256 + tid;
            int row = f >> 2, ch = (f & 3) * 8;
            const short* ga = A + (size_t)(m0 + row) * K + k0 + ch;
            const short* gb = B + (size_t)(n0 + row) * K + k0 + ch;
            async_copy16(ga, As + p * 2048 + wave * 512);
            async_copy16(gb, Bs + p * 2048 + wave * 512);
        }
        __syncthreads();
        short8 af[4], bf[4];
#pragma unroll
        for (int i = 0; i < 4; ++i)
            af[i] = *(const short8*)&As[(wm + i * 16 + mrow) * 32 + quad * 8];
#pragma unroll
        for (int j = 0; j < 4; ++j)
            bf[j] = *(const short8*)&Bs[(wn + j * 16 + mrow) * 32 + quad * 8];
#pragma unroll
        for (int i = 0; i < 4; ++i)
#pragma unroll
            for (int j = 0; j < 4; ++j)
                acc[i][j] = __builtin_amdgcn_mfma_f32_16x16x32_bf16(af[i], bf[j], acc[i][j], 0, 0, 0);
    }
#pragma unroll
    for (int i = 0; i < 4; ++i)
#pragma unroll
        for (int r = 0; r < 4; ++r) {
            int m = m0 + wm + i * 16 + quad * 4 + r;
            float* crow = C + (size_t)m * N + n0 + wn;
#pragma unroll
            for (int j = 0; j < 4; ++j)
                crow[j * 16 + mrow] = acc[i][j][r];
        }
}

// RMS of q (512, g_latent), k (128, g_kv), v (128, g_kv); q,k stored back to qkv,
// v stored as bf16 transposed vtb[(b*4+kvh)*32+d][s]. Also head-means of q and k.
__global__ __launch_bounds__(256) void rms_qkv_means(
    float* __restrict__ qkv, const float* __restrict__ g_latent,
    const float* __restrict__ g_kv,
    float* __restrict__ qmean, float* __restrict__ kmean,
    short* __restrict__ vtb) {
    int row = blockIdx.x;
    int b = row >> 11, s = row & (S_LEN - 1);
    float* p = qkv + (size_t)row * 768;
    __shared__ float sh[640];
    __shared__ float scratch[4];
    int tid = threadIdx.x;
    float v0 = p[tid], v1 = p[tid + 256], v2 = p[tid + 512];
    float ssq_q = block_reduce_sum_256(v0 * v0 + v1 * v1, scratch);
    float rq = rsqrtf(ssq_q / 512.f + EPS_);
    float q0 = v0 * rq * g_latent[tid];
    float q1 = v1 * rq * g_latent[tid + 256];
    p[tid] = q0; p[tid + 256] = q1;
    sh[tid] = q0; sh[tid + 256] = q1;
    float kpart = (tid < 128) ? v2 : 0.f;
    float vpart = (tid >= 128) ? v2 : 0.f;
    float ssq_k = block_reduce_sum_256(kpart * kpart, scratch);
    float ssq_v = block_reduce_sum_256(vpart * vpart, scratch);
    if (tid < 128) {
        float rk = rsqrtf(ssq_k / 128.f + EPS_);
        float kv = v2 * rk * g_kv[tid];
        p[512 + tid] = kv; sh[512 + tid] = kv;
    } else {
        float rv = rsqrtf(ssq_v / 128.f + EPS_);
        float vv = v2 * rv * g_kv[tid - 128];
        int d_full = tid - 128;
        vtb[((size_t)(b * 4 + (d_full >> 5)) * 32 + (d_full & 31)) * S_LEN + s] = f2bs(vv);
    }
    __syncthreads();
    if (tid < 32) {
        float sm = 0.f;
#pragma unroll
        for (int h = 0; h < 16; ++h) sm += sh[h * 32 + tid];
        qmean[(size_t)row * 32 + tid] = sm * (1.f / 16.f);
    } else if (tid < 64) {
        int d = tid - 32;
        float sm = 0.f;
#pragma unroll
        for (int h = 0; h < 4; ++h) sm += sh[512 + h * 32 + d];
        kmean[(size_t)row * 32 + d] = sm * 0.25f;
    }
}

// Grouped causal conv, 32 in / 32 out channels per group, K=3, left pad 2.
__global__ __launch_bounds__(256) void causal_conv32(
    const float* __restrict__ in, int ldin, int inoff,
    const float* __restrict__ w, float* __restrict__ out, int C) {
    int b = blockIdx.z, g = blockIdx.y, s0 = blockIdx.x * 32;
    __shared__ float wsh[32][3][32];   // [ic][tap][oc]
    __shared__ float ish[34][33];      // [pos][ic]
    int tid = threadIdx.x;
    for (int i = tid; i < 32 * 96; i += 256) {
        int oc = i / 96, r = i % 96;
        wsh[r / 3][r % 3][oc] = w[(size_t)(g * 32 + oc) * 96 + r];
    }
    for (int i = tid; i < 34 * 32; i += 256) {
        int pp = i >> 5, ic = i & 31;
        int s = s0 - 2 + pp;
        ish[pp][ic] = (s >= 0) ? in[((size_t)b * S_LEN + s) * ldin + inoff + g * 32 + ic] : 0.f;
    }
    __syncthreads();
    int sl = tid >> 3, oc0 = (tid & 7) * 4;
    float acc[4] = {0.f, 0.f, 0.f, 0.f};
    for (int ic = 0; ic < 32; ++ic) {
        float x0 = ish[sl][ic], x1 = ish[sl + 1][ic], x2 = ish[sl + 2][ic];
#pragma unroll
        for (int j = 0; j < 4; ++j)
            acc[j] += x0 * wsh[ic][0][oc0 + j] + x1 * wsh[ic][1][oc0 + j] + x2 * wsh[ic][2][oc0 + j];
    }
    float* orow = out + ((size_t)b * S_LEN + s0 + sl) * C + g * 32 + oc0;
    orow[0] = acc[0]; orow[1] = acc[1]; orow[2] = acc[2]; orow[3] = acc[3];
}

// Per-row: conv-RMS, + GAIN*mean-mix, post-RMS, per-head L2 norm, RoPE.
// Writes final q (512) and k (128) as bf16.
__global__ __launch_bounds__(256) void mix_rows(
    const float* __restrict__ convq, const float* __restrict__ convk,
    const float* __restrict__ qmean, const float* __restrict__ kmean,
    const float* __restrict__ g_conv, const float* __restrict__ g_kconv,
    const float* __restrict__ g_postq, const float* __restrict__ g_postk,
    const float* __restrict__ key_temp,
    short* __restrict__ qb, short* __restrict__ kb) {
    int row = blockIdx.x;
    int s = row & (S_LEN - 1);
    int tid = threadIdx.x;
    __shared__ float sh[640];
    __shared__ float scratch[4];
    __shared__ float hscale[20];
    float q0 = convq[(size_t)row * 512 + tid];
    float q1 = convq[(size_t)row * 512 + tid + 256];
    float k0 = (tid < 128) ? convk[(size_t)row * 128 + tid] : 0.f;
    float ssq = block_reduce_sum_256(q0 * q0 + q1 * q1, scratch);
    float r1 = rsqrtf(ssq / 512.f + EPS_);
    float ssk = block_reduce_sum_256(k0 * k0, scratch);
    float rk1 = rsqrtf(ssk / 128.f + EPS_);
    float km = kmean[(size_t)row * 32 + (tid & 31)];
    float a0 = q0 * r1 * g_conv[tid] + GAIN_ * km;
    float a1 = q1 * r1 * g_conv[tid + 256] + GAIN_ * km;
    float ak = 0.f;
    if (tid < 128) ak = k0 * rk1 * g_kconv[tid] + GAIN_ * qmean[(size_t)row * 32 + (tid & 31)];
    float ssq2 = block_reduce_sum_256(a0 * a0 + a1 * a1, scratch);
    float r2 = rsqrtf(ssq2 / 512.f + EPS_);
    float ssk2 = block_reduce_sum_256(ak * ak, scratch);
    float rk2 = rsqrtf(ssk2 / 128.f + EPS_);
    sh[tid] = a0 * r2 * g_postq[tid];
    sh[tid + 256] = a1 * r2 * g_postq[tid + 256];
    if (tid < 128) sh[512 + tid] = ak * rk2 * g_postk[tid];
    __syncthreads();
    if (tid < 16) {
        float ssh = 0.f;
        for (int d = 0; d < 32; ++d) { float x = sh[tid * 32 + d]; ssh += x * x; }
        hscale[tid] = sqrtf(32.f) / fmaxf(sqrtf(ssh), 1e-12f);
    } else if (tid < 20) {
        int h = tid - 16;
        float ssh = 0.f;
        for (int d = 0; d < 32; ++d) { float x = sh[512 + h * 32 + d]; ssh += x * x; }
        hscale[tid] = sqrtf(32.f) / fmaxf(sqrtf(ssh), 1e-12f) * key_temp[0];
    }
    __syncthreads();
    {   // q RoPE: 256 pairs
        int i0 = tid * 2;
        int h = i0 >> 5;
        int fi = (i0 & 31) >> 1;
        float sc = hscale[h];
        float x1 = sh[i0] * sc, x2 = sh[i0 + 1] * sc;
        float freq = powf(THETA_, -(float)fi / 16.f);
        float ang = (float)s * freq;
        float sn, cs;
        sincosf(ang, &sn, &cs);
        qb[(size_t)row * 512 + i0]     = f2bs(x1 * cs - x2 * sn);
        qb[(size_t)row * 512 + i0 + 1] = f2bs(x1 * sn + x2 * cs);
    }
    if (tid < 64) {  // k RoPE: 64 pairs
        int i0 = tid * 2;
        int h = i0 >> 5;
        int fi = (i0 & 31) >> 1;
        float sc = hscale[16 + h];
        float x1 = sh[512 + i0] * sc, x2 = sh[512 + i0 + 1] * sc;
        float freq = powf(THETA_, -(float)fi / 16.f);
        float ang = (float)s * freq;
        float sn, cs;
        sincosf(ang, &sn, &cs);
        kb[(size_t)row * 128 + i0]     = f2bs(x1 * cs - x2 * sn);
        kb[(size_t)row * 128 + i0 + 1] = f2bs(x1 * sn + x2 * cs);
    }
}

// MFMA flash attention. Grid (32 qtiles, 16 heads, 4 batch), 256 threads = 4 waves.
__global__ __launch_bounds__(256) void attn_mfma(
    const short* __restrict__ qb, const short* __restrict__ kb,
    const short* __restrict__ vtb, float* __restrict__ obuf) {
    int qt = blockIdx.x, h = blockIdx.y, b = blockIdx.z;
    int kvh = h >> 2;
    int s0 = qt * 64;
    __shared__ short KF[2048];   // [chunk][quad][c][j]  4KB
    __shared__ short VF[2048];   // [kc][dc][quad][c][j]  4KB
    __shared__ short PF[4096];   // per wave 1024: [kc][quad][c][j]  8KB
    int tid = threadIdx.x;
    int wave = tid >> 6, lane = tid & 63;
    int qc = lane >> 4, cc = lane & 15;

    short8 qfrag = *(const short8*)(qb +
        ((size_t)(b * S_LEN + s0 + wave * 16 + cc) * 512 + h * 32 + qc * 8));

    float4v accO[2];
    accO[0] = (float4v){0.f, 0.f, 0.f, 0.f};
    accO[1] = (float4v){0.f, 0.f, 0.f, 0.f};
    float mrow[4] = {-1e30f, -1e30f, -1e30f, -1e30f};
    float lrow[4] = {0.f, 0.f, 0.f, 0.f};
    int qpos_base = s0 + wave * 16 + qc * 4;

    for (int kt = 0; kt <= qt; ++kt) {
        __syncthreads();
        {
            int chunk = tid >> 6, quad = (tid >> 4) & 3, c = tid & 15;
            const short* src = kb +
                ((size_t)(b * S_LEN + kt * 64 + chunk * 16 + c) * 128 + kvh * 32 + quad * 8);
            *(short8*)&KF[tid * 8] = *(const short8*)src;
            int kc = tid >> 7, dc = (tid >> 6) & 1;
            const short* vsrc = vtb +
                ((size_t)((b * 4 + kvh) * 32 + dc * 16 + c) * S_LEN + kt * 64 + kc * 32 + quad * 8);
            *(short8*)&VF[tid * 8] = *(const short8*)vsrc;
        }
        __syncthreads();

        float4v sc[4];
#pragma unroll
        for (int chunk = 0; chunk < 4; ++chunk) {
            short8 kfrag = *(const short8*)&KF[chunk * 512 + lane * 8];
            float4v z = (float4v){0.f, 0.f, 0.f, 0.f};
            sc[chunk] = __builtin_amdgcn_mfma_f32_16x16x32_bf16(qfrag, kfrag, z, 0, 0, 0);
        }

#pragma unroll
        for (int r = 0; r < 4; ++r) {
            int qpos = qpos_base + r;
            float sv[4];
            float lm = -1e30f;
#pragma unroll
            for (int chunk = 0; chunk < 4; ++chunk) {
                int kpos = kt * 64 + chunk * 16 + cc;
                float v = sc[chunk][r] * SCALE_;
                v = (kpos <= qpos) ? v : -1e30f;
                sv[chunk] = v;
                lm = fmaxf(lm, v);
            }
#pragma unroll
            for (int mask = 1; mask < 16; mask <<= 1)
                lm = fmaxf(lm, __shfl_xor(lm, mask, 64));
            float mnew = fmaxf(mrow[r], lm);
            float alpha = __expf(mrow[r] - mnew);
            mrow[r] = mnew;
            accO[0][r] *= alpha;
            accO[1][r] *= alpha;
            float lsum = 0.f;
            int m_idx = qc * 4 + r;
#pragma unroll
            for (int chunk = 0; chunk < 4; ++chunk) {
                float pv = __expf(sv[chunk] - mnew);
                lsum += pv;
                int k = chunk * 16 + cc;
                PF[wave * 1024 + (k >> 5) * 512 + (((k >> 3) & 3) * 16 + m_idx) * 8 + (k & 7)]
                    = f2bs(pv);
            }
#pragma unroll
            for (int mask = 1; mask < 16; mask <<= 1)
                lsum += __shfl_xor(lsum, mask, 64);
            lrow[r] = lrow[r] * alpha + lsum;
        }

#pragma unroll
        for (int kc = 0; kc < 2; ++kc) {
            short8 pfrag = *(const short8*)&PF[wave * 1024 + kc * 512 + lane * 8];
#pragma unroll
            for (int dc = 0; dc < 2; ++dc) {
                short8 vfrag = *(const short8*)&VF[(kc * 2 + dc) * 512 + lane * 8];
                accO[dc] = __builtin_amdgcn_mfma_f32_16x16x32_bf16(pfrag, vfrag, accO[dc], 0, 0, 0);
            }
        }
    }

#pragma unroll
    for (int r = 0; r < 4; ++r) {
        float linv = 1.f / lrow[r];
        float* dst = obuf + ((size_t)(b * S_LEN + s0 + wave * 16 + qc * 4 + r) * 512 + h * 32 + cc);
        dst[0]  = accO[0][r] * linv;
        dst[16] = accO[1][r] * linv;
    }
}

// preout RMS, emits bf16 rows for the final MFMA GEMM
__global__ __launch_bounds__(256) void rms_preout_bf16(
    const float* __restrict__ buf, const float* __restrict__ g,
    short* __restrict__ outb) {
    int row = blockIdx.x;
    const float* p = buf + (size_t)row * 512;
    __shared__ float scratch[4];
    int tid = threadIdx.x;
    float v0 = p[tid], v1 = p[tid + 256];
    float ssq = block_reduce_sum_256(v0 * v0 + v1 * v1, scratch);
    float r = rsqrtf(ssq / 512.f + EPS_);
    outb[(size_t)row * 512 + tid]       = f2bs(v0 * r * g[tid]);
    outb[(size_t)row * 512 + tid + 256] = f2bs(v1 * r * g[tid + 256]);
}

extern "C" void kernel_launch(void* const* d_in, const int* in_sizes, int n_in,
                              void* d_out, int out_size, void* d_ws, size_t ws_size,
                              hipStream_t stream) {
    (void)in_sizes; (void)n_in; (void)out_size; (void)ws_size;
    const float* x        = (const float*)d_in[0];
    const float* w_q      = (const float*)d_in[1];
    const float* w_k      = (const float*)d_in[2];
    const float* w_v      = (const float*)d_in[3];
    const float* g_latent = (const float*)d_in[4];
    const float* g_kv     = (const float*)d_in[5];
    const float* conv_q_w = (const float*)d_in[6];
    const float* conv_k_w = (const float*)d_in[7];
    const float* g_conv   = (const float*)d_in[8];
    const float* g_kconv  = (const float*)d_in[9];
    const float* g_postq  = (const float*)d_in[10];
    const float* g_postk  = (const float*)d_in[11];
    const float* key_temp = (const float*)d_in[12];
    const float* g_preout = (const float*)d_in[13];
    const float* w_o      = (const float*)d_in[14];
    float* out = (float*)d_out;

    char* ws = (char*)d_ws;
    const size_t R = NROWS;
    float* qkv   = (float*)ws;                        ws += R * 768 * 4;
    float* qmean = (float*)ws;                        ws += R * 32 * 4;
    float* kmean = (float*)ws;                        ws += R * 32 * 4;
    float* convq = (float*)ws;                        ws += R * 512 * 4;
    float* convk = (float*)ws;                        ws += R * 128 * 4;
    short* qbb   = (short*)ws;                        ws += R * 512 * 2;
    short* kbb   = (short*)ws;                        ws += R * 128 * 2;
    short* vtb   = (short*)ws;                        ws += R * 128 * 2;
    short* xb    = (short*)ws;                        ws += R * 2048 * 2;
    short* wqkvb = (short*)ws;                        ws += 768 * 2048 * 2;
    short* w_ob  = (short*)ws;                        ws += 2048 * 512 * 2;
    float* attn  = convq;          // convq consumed by mix_rows before attn writes
    short* attnb = xb;             // xb dead after QKV gemm

    dim3 blk(256);
    cvt_bf16<<<(NROWS * 2048) / 1024, blk, 0, stream>>>(x, xb, NROWS * 2048);
    cvt_bf16<<<(512 * 2048) / 1024, blk, 0, stream>>>(w_q, wqkvb, 512 * 2048);
    cvt_bf16<<<(128 * 2048) / 1024, blk, 0, stream>>>(w_k, wqkvb + 512 * 2048, 128 * 2048);
    cvt_bf16<<<(128 * 2048) / 1024, blk, 0, stream>>>(w_v, wqkvb + 640 * 2048, 128 * 2048);
    cvt_bf16<<<(2048 * 512) / 1024, blk, 0, stream>>>(w_o, w_ob, 2048 * 512);

    gemm_bf16_mfma<<<dim3(6, 64), blk, 0, stream>>>(xb, wqkvb, qkv, 768, 2048);
    rms_qkv_means<<<NROWS, blk, 0, stream>>>(qkv, g_latent, g_kv, qmean, kmean, vtb);
    causal_conv32<<<dim3(64, 16, 4), blk, 0, stream>>>(qkv, 768, 0, conv_q_w, convq, 512);
    causal_conv32<<<dim3(64, 4, 4), blk, 0, stream>>>(qkv, 768, 512, conv_k_w, convk, 128);
    mix_rows<<<NROWS, blk, 0, stream>>>(convq, convk, qmean, kmean, g_conv, g_kconv,
                                        g_postq, g_postk, key_temp, qbb, kbb);
    attn_mfma<<<dim3(32, 16, 4), blk, 0, stream>>>(qbb, kbb, vtb, attn);
    rms_preout_bf16<<<NROWS, blk, 0, stream>>>(attn, g_preout, attnb);
    gemm_bf16_mfma<<<dim3(16, 64), blk, 0, stream>>>(attnb, w_ob, out, 2048, 512);
}

// Round 4
// 455.056 us; speedup vs baseline: 5.3539x; 1.1194x over previous
//
#include <hip/hip_runtime.h>
#include <hip/hip_bf16.h>
#include <math.h>

constexpr int S_LEN = 2048;
constexpr int B_SZ  = 4;
constexpr int NROWS = B_SZ * S_LEN;   // 8192
constexpr float GAIN_  = 0.25f;
constexpr float EPS_   = 1e-6f;
constexpr float THETA_ = 10000.0f;
constexpr float SCALE_ = 0.17677669529663687f; // 1/sqrt(32)
constexpr float LOG2E_ = 1.44269504f;

typedef __attribute__((ext_vector_type(8))) short short8;
typedef __attribute__((ext_vector_type(4))) float float4v;

__device__ __forceinline__ short f2bs(float f) {
    __hip_bfloat16 h = __float2bfloat16(f);
    short r;
    __builtin_memcpy(&r, &h, 2);
    return r;
}

__device__ __forceinline__ void async_copy16(const short* g, short* l) {
    __builtin_amdgcn_global_load_lds(
        (const __attribute__((address_space(1))) void*)g,
        (__attribute__((address_space(3))) void*)l, 16, 0, 0);
}

__device__ __forceinline__ float block_reduce_sum_256(float v, float* scratch) {
    __syncthreads();
    for (int off = 32; off > 0; off >>= 1)
        v += __shfl_down(v, off, 64);
    int lane = threadIdx.x & 63;
    int wid  = threadIdx.x >> 6;
    if (lane == 0) scratch[wid] = v;
    __syncthreads();
    if (threadIdx.x == 0) scratch[0] = scratch[0] + scratch[1] + scratch[2] + scratch[3];
    __syncthreads();
    return scratch[0];
}

// fp32 -> bf16 cast, n % 4 == 0
__global__ __launch_bounds__(256) void cvt_bf16(
    const float* __restrict__ src, short* __restrict__ dst, int n) {
    int i = (blockIdx.x * 256 + threadIdx.x) * 4;
    if (i >= n) return;
    float4 v = *(const float4*)(src + i);
    dst[i + 0] = f2bs(v.x); dst[i + 1] = f2bs(v.y);
    dst[i + 2] = f2bs(v.z); dst[i + 3] = f2bs(v.w);
}

// C[M x N] fp32 = A[M x K](bf16) @ B[N x K](bf16)^T.  M%128==0, N%128==0, K%32==0.
__global__ __launch_bounds__(256) void gemm_bf16_mfma(
    const short* __restrict__ A, const short* __restrict__ B,
    float* __restrict__ C, int N, int K) {
    __shared__ short As[128 * 32];
    __shared__ short Bs[128 * 32];
    int tid = threadIdx.x;
    int wave = tid >> 6, lane = tid & 63;
    int m0 = blockIdx.y * 128, n0 = blockIdx.x * 128;
    int wm = (wave >> 1) * 64, wn = (wave & 1) * 64;
    int mrow = lane & 15, quad = lane >> 4;
    float4v acc[4][4] = {};
    for (int k0 = 0; k0 < K; k0 += 32) {
        __syncthreads();
#pragma unroll
        for (int p = 0; p < 2; ++p) {
            int f = p * 256 + tid;
            int row = f >> 2, ch = (f & 3) * 8;
            const short* ga = A + (size_t)(m0 + row) * K + k0 + ch;
            const short* gb = B + (size_t)(n0 + row) * K + k0 + ch;
            async_copy16(ga, As + p * 2048 + wave * 512);
            async_copy16(gb, Bs + p * 2048 + wave * 512);
        }
        __syncthreads();
        short8 af[4], bf[4];
#pragma unroll
        for (int i = 0; i < 4; ++i)
            af[i] = *(const short8*)&As[(wm + i * 16 + mrow) * 32 + quad * 8];
#pragma unroll
        for (int j = 0; j < 4; ++j)
            bf[j] = *(const short8*)&Bs[(wn + j * 16 + mrow) * 32 + quad * 8];
#pragma unroll
        for (int i = 0; i < 4; ++i)
#pragma unroll
            for (int j = 0; j < 4; ++j)
                acc[i][j] = __builtin_amdgcn_mfma_f32_16x16x32_bf16(af[i], bf[j], acc[i][j], 0, 0, 0);
    }
#pragma unroll
    for (int i = 0; i < 4; ++i)
#pragma unroll
        for (int r = 0; r < 4; ++r) {
            int m = m0 + wm + i * 16 + quad * 4 + r;
            float* crow = C + (size_t)m * N + n0 + wn;
#pragma unroll
            for (int j = 0; j < 4; ++j)
                crow[j * 16 + mrow] = acc[i][j][r];
        }
}

// RMS of q (512, g_latent), k (128, g_kv), v (128, g_kv); q,k stored back to qkv,
// v stored as bf16 transposed vtb[(b*4+kvh)*32+d][s]. Also head-means of q and k.
__global__ __launch_bounds__(256) void rms_qkv_means(
    float* __restrict__ qkv, const float* __restrict__ g_latent,
    const float* __restrict__ g_kv,
    float* __restrict__ qmean, float* __restrict__ kmean,
    short* __restrict__ vtb) {
    int row = blockIdx.x;
    int b = row >> 11, s = row & (S_LEN - 1);
    float* p = qkv + (size_t)row * 768;
    __shared__ float sh[640];
    __shared__ float scratch[4];
    int tid = threadIdx.x;
    float v0 = p[tid], v1 = p[tid + 256], v2 = p[tid + 512];
    float ssq_q = block_reduce_sum_256(v0 * v0 + v1 * v1, scratch);
    float rq = rsqrtf(ssq_q / 512.f + EPS_);
    float q0 = v0 * rq * g_latent[tid];
    float q1 = v1 * rq * g_latent[tid + 256];
    p[tid] = q0; p[tid + 256] = q1;
    sh[tid] = q0; sh[tid + 256] = q1;
    float kpart = (tid < 128) ? v2 : 0.f;
    float vpart = (tid >= 128) ? v2 : 0.f;
    float ssq_k = block_reduce_sum_256(kpart * kpart, scratch);
    float ssq_v = block_reduce_sum_256(vpart * vpart, scratch);
    if (tid < 128) {
        float rk = rsqrtf(ssq_k / 128.f + EPS_);
        float kv = v2 * rk * g_kv[tid];
        p[512 + tid] = kv; sh[512 + tid] = kv;
    } else {
        float rv = rsqrtf(ssq_v / 128.f + EPS_);
        float vv = v2 * rv * g_kv[tid - 128];
        int d_full = tid - 128;
        vtb[((size_t)(b * 4 + (d_full >> 5)) * 32 + (d_full & 31)) * S_LEN + s] = f2bs(vv);
    }
    __syncthreads();
    if (tid < 32) {
        float sm = 0.f;
#pragma unroll
        for (int h = 0; h < 16; ++h) sm += sh[h * 32 + tid];
        qmean[(size_t)row * 32 + tid] = sm * (1.f / 16.f);
    } else if (tid < 64) {
        int d = tid - 32;
        float sm = 0.f;
#pragma unroll
        for (int h = 0; h < 4; ++h) sm += sh[512 + h * 32 + d];
        kmean[(size_t)row * 32 + d] = sm * 0.25f;
    }
}

// Grouped causal conv, 32 in / 32 out channels per group, K=3, left pad 2.
__global__ __launch_bounds__(256) void causal_conv32(
    const float* __restrict__ in, int ldin, int inoff,
    const float* __restrict__ w, float* __restrict__ out, int C) {
    int b = blockIdx.z, g = blockIdx.y, s0 = blockIdx.x * 32;
    __shared__ float wsh[32][3][32];   // [ic][tap][oc]
    __shared__ float ish[34][33];      // [pos][ic]
    int tid = threadIdx.x;
    for (int i = tid; i < 32 * 96; i += 256) {
        int oc = i / 96, r = i % 96;
        wsh[r / 3][r % 3][oc] = w[(size_t)(g * 32 + oc) * 96 + r];
    }
    for (int i = tid; i < 34 * 32; i += 256) {
        int pp = i >> 5, ic = i & 31;
        int s = s0 - 2 + pp;
        ish[pp][ic] = (s >= 0) ? in[((size_t)b * S_LEN + s) * ldin + inoff + g * 32 + ic] : 0.f;
    }
    __syncthreads();
    int sl = tid >> 3, oc0 = (tid & 7) * 4;
    float acc[4] = {0.f, 0.f, 0.f, 0.f};
    for (int ic = 0; ic < 32; ++ic) {
        float x0 = ish[sl][ic], x1 = ish[sl + 1][ic], x2 = ish[sl + 2][ic];
#pragma unroll
        for (int j = 0; j < 4; ++j)
            acc[j] += x0 * wsh[ic][0][oc0 + j] + x1 * wsh[ic][1][oc0 + j] + x2 * wsh[ic][2][oc0 + j];
    }
    float* orow = out + ((size_t)b * S_LEN + s0 + sl) * C + g * 32 + oc0;
    orow[0] = acc[0]; orow[1] = acc[1]; orow[2] = acc[2]; orow[3] = acc[3];
}

// Per-row: conv-RMS, + GAIN*mean-mix, post-RMS, per-head L2 norm, RoPE.
// Writes final q (512, pre-scaled by SCALE_) and k (128) as bf16.
__global__ __launch_bounds__(256) void mix_rows(
    const float* __restrict__ convq, const float* __restrict__ convk,
    const float* __restrict__ qmean, const float* __restrict__ kmean,
    const float* __restrict__ g_conv, const float* __restrict__ g_kconv,
    const float* __restrict__ g_postq, const float* __restrict__ g_postk,
    const float* __restrict__ key_temp,
    short* __restrict__ qb, short* __restrict__ kb) {
    int row = blockIdx.x;
    int s = row & (S_LEN - 1);
    int tid = threadIdx.x;
    __shared__ float sh[640];
    __shared__ float scratch[4];
    __shared__ float hscale[20];
    float q0 = convq[(size_t)row * 512 + tid];
    float q1 = convq[(size_t)row * 512 + tid + 256];
    float k0 = (tid < 128) ? convk[(size_t)row * 128 + tid] : 0.f;
    float ssq = block_reduce_sum_256(q0 * q0 + q1 * q1, scratch);
    float r1 = rsqrtf(ssq / 512.f + EPS_);
    float ssk = block_reduce_sum_256(k0 * k0, scratch);
    float rk1 = rsqrtf(ssk / 128.f + EPS_);
    float km = kmean[(size_t)row * 32 + (tid & 31)];
    float a0 = q0 * r1 * g_conv[tid] + GAIN_ * km;
    float a1 = q1 * r1 * g_conv[tid + 256] + GAIN_ * km;
    float ak = 0.f;
    if (tid < 128) ak = k0 * rk1 * g_kconv[tid] + GAIN_ * qmean[(size_t)row * 32 + (tid & 31)];
    float ssq2 = block_reduce_sum_256(a0 * a0 + a1 * a1, scratch);
    float r2 = rsqrtf(ssq2 / 512.f + EPS_);
    float ssk2 = block_reduce_sum_256(ak * ak, scratch);
    float rk2 = rsqrtf(ssk2 / 128.f + EPS_);
    sh[tid] = a0 * r2 * g_postq[tid];
    sh[tid + 256] = a1 * r2 * g_postq[tid + 256];
    if (tid < 128) sh[512 + tid] = ak * rk2 * g_postk[tid];
    __syncthreads();
    if (tid < 16) {
        float ssh = 0.f;
        for (int d = 0; d < 32; ++d) { float x = sh[tid * 32 + d]; ssh += x * x; }
        // sqrt(32) * SCALE_ == 1, SCALE_ folded into q
        hscale[tid] = 1.f / fmaxf(sqrtf(ssh), 1e-12f);
    } else if (tid < 20) {
        int h = tid - 16;
        float ssh = 0.f;
        for (int d = 0; d < 32; ++d) { float x = sh[512 + h * 32 + d]; ssh += x * x; }
        hscale[tid] = sqrtf(32.f) / fmaxf(sqrtf(ssh), 1e-12f) * key_temp[0];
    }
    __syncthreads();
    {   // q RoPE: 256 pairs
        int i0 = tid * 2;
        int h = i0 >> 5;
        int fi = (i0 & 31) >> 1;
        float sc = hscale[h];
        float x1 = sh[i0] * sc, x2 = sh[i0 + 1] * sc;
        float freq = powf(THETA_, -(float)fi / 16.f);
        float ang = (float)s * freq;
        float sn, cs;
        sincosf(ang, &sn, &cs);
        qb[(size_t)row * 512 + i0]     = f2bs(x1 * cs - x2 * sn);
        qb[(size_t)row * 512 + i0 + 1] = f2bs(x1 * sn + x2 * cs);
    }
    if (tid < 64) {  // k RoPE: 64 pairs
        int i0 = tid * 2;
        int h = i0 >> 5;
        int fi = (i0 & 31) >> 1;
        float sc = hscale[16 + h];
        float x1 = sh[512 + i0] * sc, x2 = sh[512 + i0 + 1] * sc;
        float freq = powf(THETA_, -(float)fi / 16.f);
        float ang = (float)s * freq;
        float sn, cs;
        sincosf(ang, &sn, &cs);
        kb[(size_t)row * 128 + i0]     = f2bs(x1 * cs - x2 * sn);
        kb[(size_t)row * 128 + i0 + 1] = f2bs(x1 * sn + x2 * cs);
    }
}

// MFMA flash attention, fixed-shift softmax (scores bounded by sqrt(32)*key_temp).
// Computes S^T = K·Q^T so P lands lane-contiguous for the LDS transpose.
__global__ __launch_bounds__(256) void attn_mfma(
    const short* __restrict__ qb, const short* __restrict__ kb,
    const short* __restrict__ vtb, float* __restrict__ obuf,
    const float* __restrict__ key_temp) {
    int qt = blockIdx.x, h = blockIdx.y, b = blockIdx.z;
    int kvh = h >> 2;
    int s0 = qt * 64;
    __shared__ short KF[2048];                    // A-frags of K  4KB
    __shared__ short VF[2048];                    // B-frags of V  4KB
    __shared__ __align__(16) short PF[4 * 16 * 72]; // per-wave P [qrow][k] pad72  9KB
    int tid = threadIdx.x;
    int wave = tid >> 6, lane = tid & 63;
    int cc = lane & 15, qc = lane >> 4;
    short* PFw = PF + wave * 16 * 72;

    // Q B-frag (SCALE_ pre-folded): lane = qcol + 16*dquad
    short8 qfrag = *(const short8*)(qb +
        ((size_t)(b * S_LEN + s0 + wave * 16 + cc) * 512 + h * 32 + qc * 8));

    float4v accO[2];
    accO[0] = (float4v){0.f, 0.f, 0.f, 0.f};
    accO[1] = (float4v){0.f, 0.f, 0.f, 0.f};
    float lpart = 0.f;
    // exp(s - C) = exp2(s*log2e + shift2), C = sqrt(32)*key_temp >= max score
    float shift2 = -5.6568543f * key_temp[0] * LOG2E_;
    int qpos = s0 + wave * 16 + cc;   // this lane's q column

    for (int kt = 0; kt <= qt; ++kt) {
        __syncthreads();
        {
            int chunk = tid >> 6, quad = (tid >> 4) & 3, c = tid & 15;
            const short* src = kb +
                ((size_t)(b * S_LEN + kt * 64 + chunk * 16 + c) * 128 + kvh * 32 + quad * 8);
            *(short8*)&KF[tid * 8] = *(const short8*)src;
            int kc = tid >> 7, dc = (tid >> 6) & 1;
            const short* vsrc = vtb +
                ((size_t)((b * 4 + kvh) * 32 + dc * 16 + c) * S_LEN + kt * 64 + kc * 32 + quad * 8);
            *(short8*)&VF[tid * 8] = *(const short8*)vsrc;
        }
        __syncthreads();

        // S^T = K·Q^T: C[m=kpos][n=qcol], lane holds kpos = chunk*16 + qc*4 + reg
        float4v st[4];
#pragma unroll
        for (int chunk = 0; chunk < 4; ++chunk) {
            short8 kfrag = *(const short8*)&KF[chunk * 512 + lane * 8];
            float4v z = (float4v){0.f, 0.f, 0.f, 0.f};
            st[chunk] = __builtin_amdgcn_mfma_f32_16x16x32_bf16(kfrag, qfrag, z, 0, 0, 0);
        }

        bool diag = (kt == qt);
#pragma unroll
        for (int chunk = 0; chunk < 4; ++chunk) {
            float pv[4];
#pragma unroll
            for (int r = 0; r < 4; ++r) {
                float e = exp2f(fmaf(st[chunk][r], LOG2E_, shift2));
                if (diag) {
                    int kpos = kt * 64 + chunk * 16 + qc * 4 + r;
                    e = (kpos <= qpos) ? e : 0.f;
                }
                pv[r] = e;
                lpart += e;
            }
            unsigned u0 = (unsigned)(unsigned short)f2bs(pv[0]) |
                          ((unsigned)(unsigned short)f2bs(pv[1]) << 16);
            unsigned u1 = (unsigned)(unsigned short)f2bs(pv[2]) |
                          ((unsigned)(unsigned short)f2bs(pv[3]) << 16);
            *(uint2*)&PFw[cc * 72 + chunk * 16 + qc * 4] = make_uint2(u0, u1);
        }

        // PV: O[qrow][d] += P·V   (pfrag A[m=qrow][k], lane = qrow + 16*kquad)
#pragma unroll
        for (int kc = 0; kc < 2; ++kc) {
            short8 pfrag = *(const short8*)&PFw[cc * 72 + kc * 32 + qc * 8];
#pragma unroll
            for (int dc = 0; dc < 2; ++dc) {
                short8 vfrag = *(const short8*)&VF[(kc * 2 + dc) * 512 + lane * 8];
                accO[dc] = __builtin_amdgcn_mfma_f32_16x16x32_bf16(pfrag, vfrag, accO[dc], 0, 0, 0);
            }
        }
    }

    // reduce l across the 4 quads sharing a q-column, then fetch per-row inverses
    lpart += __shfl_xor(lpart, 16, 64);
    lpart += __shfl_xor(lpart, 32, 64);
#pragma unroll
    for (int r = 0; r < 4; ++r) {
        float linv = 1.f / __shfl(lpart, qc * 4 + r, 64);
        float* dst = obuf + ((size_t)(b * S_LEN + s0 + wave * 16 + qc * 4 + r) * 512 + h * 32 + cc);
        dst[0]  = accO[0][r] * linv;
        dst[16] = accO[1][r] * linv;
    }
}

// preout RMS, emits bf16 rows for the final MFMA GEMM
__global__ __launch_bounds__(256) void rms_preout_bf16(
    const float* __restrict__ buf, const float* __restrict__ g,
    short* __restrict__ outb) {
    int row = blockIdx.x;
    const float* p = buf + (size_t)row * 512;
    __shared__ float scratch[4];
    int tid = threadIdx.x;
    float v0 = p[tid], v1 = p[tid + 256];
    float ssq = block_reduce_sum_256(v0 * v0 + v1 * v1, scratch);
    float r = rsqrtf(ssq / 512.f + EPS_);
    outb[(size_t)row * 512 + tid]       = f2bs(v0 * r * g[tid]);
    outb[(size_t)row * 512 + tid + 256] = f2bs(v1 * r * g[tid + 256]);
}

extern "C" void kernel_launch(void* const* d_in, const int* in_sizes, int n_in,
                              void* d_out, int out_size, void* d_ws, size_t ws_size,
                              hipStream_t stream) {
    (void)in_sizes; (void)n_in; (void)out_size; (void)ws_size;
    const float* x        = (const float*)d_in[0];
    const float* w_q      = (const float*)d_in[1];
    const float* w_k      = (const float*)d_in[2];
    const float* w_v      = (const float*)d_in[3];
    const float* g_latent = (const float*)d_in[4];
    const float* g_kv     = (const float*)d_in[5];
    const float* conv_q_w = (const float*)d_in[6];
    const float* conv_k_w = (const float*)d_in[7];
    const float* g_conv   = (const float*)d_in[8];
    const float* g_kconv  = (const float*)d_in[9];
    const float* g_postq  = (const float*)d_in[10];
    const float* g_postk  = (const float*)d_in[11];
    const float* key_temp = (const float*)d_in[12];
    const float* g_preout = (const float*)d_in[13];
    const float* w_o      = (const float*)d_in[14];
    float* out = (float*)d_out;

    char* ws = (char*)d_ws;
    const size_t R = NROWS;
    float* qkv   = (float*)ws;                        ws += R * 768 * 4;
    float* qmean = (float*)ws;                        ws += R * 32 * 4;
    float* kmean = (float*)ws;                        ws += R * 32 * 4;
    float* convq = (float*)ws;                        ws += R * 512 * 4;
    float* convk = (float*)ws;                        ws += R * 128 * 4;
    short* qbb   = (short*)ws;                        ws += R * 512 * 2;
    short* kbb   = (short*)ws;                        ws += R * 128 * 2;
    short* vtb   = (short*)ws;                        ws += R * 128 * 2;
    short* xb    = (short*)ws;                        ws += R * 2048 * 2;
    short* wqkvb = (short*)ws;                        ws += 768 * 2048 * 2;
    short* w_ob  = (short*)ws;                        ws += 2048 * 512 * 2;
    float* attn  = convq;          // convq consumed by mix_rows before attn writes
    short* attnb = xb;             // xb dead after QKV gemm

    dim3 blk(256);
    cvt_bf16<<<(NROWS * 2048) / 1024, blk, 0, stream>>>(x, xb, NROWS * 2048);
    cvt_bf16<<<(512 * 2048) / 1024, blk, 0, stream>>>(w_q, wqkvb, 512 * 2048);
    cvt_bf16<<<(128 * 2048) / 1024, blk, 0, stream>>>(w_k, wqkvb + 512 * 2048, 128 * 2048);
    cvt_bf16<<<(128 * 2048) / 1024, blk, 0, stream>>>(w_v, wqkvb + 640 * 2048, 128 * 2048);
    cvt_bf16<<<(2048 * 512) / 1024, blk, 0, stream>>>(w_o, w_ob, 2048 * 512);

    gemm_bf16_mfma<<<dim3(6, 64), blk, 0, stream>>>(xb, wqkvb, qkv, 768, 2048);
    rms_qkv_means<<<NROWS, blk, 0, stream>>>(qkv, g_latent, g_kv, qmean, kmean, vtb);
    causal_conv32<<<dim3(64, 16, 4), blk, 0, stream>>>(qkv, 768, 0, conv_q_w, convq, 512);
    causal_conv32<<<dim3(64, 4, 4), blk, 0, stream>>>(qkv, 768, 512, conv_k_w, convk, 128);
    mix_rows<<<NROWS, blk, 0, stream>>>(convq, convk, qmean, kmean, g_conv, g_kconv,
                                        g_postq, g_postk, key_temp, qbb, kbb);
    attn_mfma<<<dim3(32, 16, 4), blk, 0, stream>>>(qbb, kbb, vtb, attn, key_temp);
    rms_preout_bf16<<<NROWS, blk, 0, stream>>>(attn, g_preout, attnb);
    gemm_bf16_mfma<<<dim3(16, 64), blk, 0, stream>>>(attnb, w_ob, out, 2048, 512);
}

// Round 5
// 423.623 us; speedup vs baseline: 5.7512x; 1.0742x over previous
//
#include <hip/hip_runtime.h>
#include <hip/hip_bf16.h>
#include <math.h>

constexpr int S_LEN = 2048;
constexpr int B_SZ  = 4;
constexpr int NROWS = B_SZ * S_LEN;   // 8192
constexpr float GAIN_  = 0.25f;
constexpr float EPS_   = 1e-6f;
constexpr float THETA_ = 10000.0f;
constexpr float SCALE_ = 0.17677669529663687f; // 1/sqrt(32)
constexpr float LOG2E_ = 1.44269504f;

typedef __attribute__((ext_vector_type(8))) short short8;
typedef __attribute__((ext_vector_type(4))) float float4v;

__device__ __forceinline__ short f2bs(float f) {
    __hip_bfloat16 h = __float2bfloat16(f);
    short r;
    __builtin_memcpy(&r, &h, 2);
    return r;
}

__device__ __forceinline__ void async_copy16(const short* g, short* l) {
    __builtin_amdgcn_global_load_lds(
        (const __attribute__((address_space(1))) void*)g,
        (__attribute__((address_space(3))) void*)l, 16, 0, 0);
}

__device__ __forceinline__ float block_reduce_sum_256(float v, float* scratch) {
    __syncthreads();
    for (int off = 32; off > 0; off >>= 1)
        v += __shfl_down(v, off, 64);
    int lane = threadIdx.x & 63;
    int wid  = threadIdx.x >> 6;
    if (lane == 0) scratch[wid] = v;
    __syncthreads();
    if (threadIdx.x == 0) scratch[0] = scratch[0] + scratch[1] + scratch[2] + scratch[3];
    __syncthreads();
    return scratch[0];
}

// fp32 -> bf16 cast, n % 4 == 0
__global__ __launch_bounds__(256) void cvt_bf16(
    const float* __restrict__ src, short* __restrict__ dst, int n) {
    int i = (blockIdx.x * 256 + threadIdx.x) * 4;
    if (i >= n) return;
    float4 v = *(const float4*)(src + i);
    dst[i + 0] = f2bs(v.x); dst[i + 1] = f2bs(v.y);
    dst[i + 2] = f2bs(v.z); dst[i + 3] = f2bs(v.w);
}

// C[M x N] fp32 = A[M x K](bf16) @ B[N x K](bf16)^T.  M%128==0, N%128==0, K%32==0.
__global__ __launch_bounds__(256) void gemm_bf16_mfma(
    const short* __restrict__ A, const short* __restrict__ B,
    float* __restrict__ C, int N, int K) {
    __shared__ short As[128 * 32];
    __shared__ short Bs[128 * 32];
    int tid = threadIdx.x;
    int wave = tid >> 6, lane = tid & 63;
    int m0 = blockIdx.y * 128, n0 = blockIdx.x * 128;
    int wm = (wave >> 1) * 64, wn = (wave & 1) * 64;
    int mrow = lane & 15, quad = lane >> 4;
    float4v acc[4][4] = {};
    for (int k0 = 0; k0 < K; k0 += 32) {
        __syncthreads();
#pragma unroll
        for (int p = 0; p < 2; ++p) {
            int f = p * 256 + tid;
            int row = f >> 2, ch = (f & 3) * 8;
            const short* ga = A + (size_t)(m0 + row) * K + k0 + ch;
            const short* gb = B + (size_t)(n0 + row) * K + k0 + ch;
            async_copy16(ga, As + p * 2048 + wave * 512);
            async_copy16(gb, Bs + p * 2048 + wave * 512);
        }
        __syncthreads();
        short8 af[4], bf[4];
#pragma unroll
        for (int i = 0; i < 4; ++i)
            af[i] = *(const short8*)&As[(wm + i * 16 + mrow) * 32 + quad * 8];
#pragma unroll
        for (int j = 0; j < 4; ++j)
            bf[j] = *(const short8*)&Bs[(wn + j * 16 + mrow) * 32 + quad * 8];
#pragma unroll
        for (int i = 0; i < 4; ++i)
#pragma unroll
            for (int j = 0; j < 4; ++j)
                acc[i][j] = __builtin_amdgcn_mfma_f32_16x16x32_bf16(af[i], bf[j], acc[i][j], 0, 0, 0);
    }
#pragma unroll
    for (int i = 0; i < 4; ++i)
#pragma unroll
        for (int r = 0; r < 4; ++r) {
            int m = m0 + wm + i * 16 + quad * 4 + r;
            float* crow = C + (size_t)m * N + n0 + wn;
#pragma unroll
            for (int j = 0; j < 4; ++j)
                crow[j * 16 + mrow] = acc[i][j][r];
        }
}

// RMS of q (512, g_latent), k (128, g_kv), v (128, g_kv); q,k stored back to qkv,
// v stored as bf16 transposed vtb[(b*4+kvh)*32+d][s]. Also head-means of q and k.
__global__ __launch_bounds__(256) void rms_qkv_means(
    float* __restrict__ qkv, const float* __restrict__ g_latent,
    const float* __restrict__ g_kv,
    float* __restrict__ qmean, float* __restrict__ kmean,
    short* __restrict__ vtb) {
    int row = blockIdx.x;
    int b = row >> 11, s = row & (S_LEN - 1);
    float* p = qkv + (size_t)row * 768;
    __shared__ float sh[640];
    __shared__ float scratch[4];
    int tid = threadIdx.x;
    float v0 = p[tid], v1 = p[tid + 256], v2 = p[tid + 512];
    float ssq_q = block_reduce_sum_256(v0 * v0 + v1 * v1, scratch);
    float rq = rsqrtf(ssq_q / 512.f + EPS_);
    float q0 = v0 * rq * g_latent[tid];
    float q1 = v1 * rq * g_latent[tid + 256];
    p[tid] = q0; p[tid + 256] = q1;
    sh[tid] = q0; sh[tid + 256] = q1;
    float kpart = (tid < 128) ? v2 : 0.f;
    float vpart = (tid >= 128) ? v2 : 0.f;
    float ssq_k = block_reduce_sum_256(kpart * kpart, scratch);
    float ssq_v = block_reduce_sum_256(vpart * vpart, scratch);
    if (tid < 128) {
        float rk = rsqrtf(ssq_k / 128.f + EPS_);
        float kv = v2 * rk * g_kv[tid];
        p[512 + tid] = kv; sh[512 + tid] = kv;
    } else {
        float rv = rsqrtf(ssq_v / 128.f + EPS_);
        float vv = v2 * rv * g_kv[tid - 128];
        int d_full = tid - 128;
        vtb[((size_t)(b * 4 + (d_full >> 5)) * 32 + (d_full & 31)) * S_LEN + s] = f2bs(vv);
    }
    __syncthreads();
    if (tid < 32) {
        float sm = 0.f;
#pragma unroll
        for (int h = 0; h < 16; ++h) sm += sh[h * 32 + tid];
        qmean[(size_t)row * 32 + tid] = sm * (1.f / 16.f);
    } else if (tid < 64) {
        int d = tid - 32;
        float sm = 0.f;
#pragma unroll
        for (int h = 0; h < 4; ++h) sm += sh[512 + h * 32 + d];
        kmean[(size_t)row * 32 + d] = sm * 0.25f;
    }
}

// Grouped causal conv, 32 in / 32 out channels per group, K=3, left pad 2.
__global__ __launch_bounds__(256) void causal_conv32(
    const float* __restrict__ in, int ldin, int inoff,
    const float* __restrict__ w, float* __restrict__ out, int C) {
    int b = blockIdx.z, g = blockIdx.y, s0 = blockIdx.x * 32;
    __shared__ float wsh[32][3][32];   // [ic][tap][oc]
    __shared__ float ish[34][33];      // [pos][ic]
    int tid = threadIdx.x;
    for (int i = tid; i < 32 * 96; i += 256) {
        int oc = i / 96, r = i % 96;
        wsh[r / 3][r % 3][oc] = w[(size_t)(g * 32 + oc) * 96 + r];
    }
    for (int i = tid; i < 34 * 32; i += 256) {
        int pp = i >> 5, ic = i & 31;
        int s = s0 - 2 + pp;
        ish[pp][ic] = (s >= 0) ? in[((size_t)b * S_LEN + s) * ldin + inoff + g * 32 + ic] : 0.f;
    }
    __syncthreads();
    int sl = tid >> 3, oc0 = (tid & 7) * 4;
    float acc[4] = {0.f, 0.f, 0.f, 0.f};
    for (int ic = 0; ic < 32; ++ic) {
        float x0 = ish[sl][ic], x1 = ish[sl + 1][ic], x2 = ish[sl + 2][ic];
#pragma unroll
        for (int j = 0; j < 4; ++j)
            acc[j] += x0 * wsh[ic][0][oc0 + j] + x1 * wsh[ic][1][oc0 + j] + x2 * wsh[ic][2][oc0 + j];
    }
    float* orow = out + ((size_t)b * S_LEN + s0 + sl) * C + g * 32 + oc0;
    orow[0] = acc[0]; orow[1] = acc[1]; orow[2] = acc[2]; orow[3] = acc[3];
}

// Per-row: conv-RMS, + GAIN*mean-mix, post-RMS, per-head L2 norm, RoPE.
// Writes final q (512, pre-scaled by SCALE_) and k (128) as bf16.
__global__ __launch_bounds__(256) void mix_rows(
    const float* __restrict__ convq, const float* __restrict__ convk,
    const float* __restrict__ qmean, const float* __restrict__ kmean,
    const float* __restrict__ g_conv, const float* __restrict__ g_kconv,
    const float* __restrict__ g_postq, const float* __restrict__ g_postk,
    const float* __restrict__ key_temp,
    short* __restrict__ qb, short* __restrict__ kb) {
    int row = blockIdx.x;
    int s = row & (S_LEN - 1);
    int tid = threadIdx.x;
    __shared__ float sh[640];
    __shared__ float scratch[4];
    __shared__ float hscale[20];
    float q0 = convq[(size_t)row * 512 + tid];
    float q1 = convq[(size_t)row * 512 + tid + 256];
    float k0 = (tid < 128) ? convk[(size_t)row * 128 + tid] : 0.f;
    float ssq = block_reduce_sum_256(q0 * q0 + q1 * q1, scratch);
    float r1 = rsqrtf(ssq / 512.f + EPS_);
    float ssk = block_reduce_sum_256(k0 * k0, scratch);
    float rk1 = rsqrtf(ssk / 128.f + EPS_);
    float km = kmean[(size_t)row * 32 + (tid & 31)];
    float a0 = q0 * r1 * g_conv[tid] + GAIN_ * km;
    float a1 = q1 * r1 * g_conv[tid + 256] + GAIN_ * km;
    float ak = 0.f;
    if (tid < 128) ak = k0 * rk1 * g_kconv[tid] + GAIN_ * qmean[(size_t)row * 32 + (tid & 31)];
    float ssq2 = block_reduce_sum_256(a0 * a0 + a1 * a1, scratch);
    float r2 = rsqrtf(ssq2 / 512.f + EPS_);
    float ssk2 = block_reduce_sum_256(ak * ak, scratch);
    float rk2 = rsqrtf(ssk2 / 128.f + EPS_);
    sh[tid] = a0 * r2 * g_postq[tid];
    sh[tid + 256] = a1 * r2 * g_postq[tid + 256];
    if (tid < 128) sh[512 + tid] = ak * rk2 * g_postk[tid];
    __syncthreads();
    if (tid < 16) {
        float ssh = 0.f;
        for (int d = 0; d < 32; ++d) { float x = sh[tid * 32 + d]; ssh += x * x; }
        // sqrt(32) * SCALE_ == 1, SCALE_ folded into q
        hscale[tid] = 1.f / fmaxf(sqrtf(ssh), 1e-12f);
    } else if (tid < 20) {
        int h = tid - 16;
        float ssh = 0.f;
        for (int d = 0; d < 32; ++d) { float x = sh[512 + h * 32 + d]; ssh += x * x; }
        hscale[tid] = sqrtf(32.f) / fmaxf(sqrtf(ssh), 1e-12f) * key_temp[0];
    }
    __syncthreads();
    {   // q RoPE: 256 pairs
        int i0 = tid * 2;
        int h = i0 >> 5;
        int fi = (i0 & 31) >> 1;
        float sc = hscale[h];
        float x1 = sh[i0] * sc, x2 = sh[i0 + 1] * sc;
        float freq = powf(THETA_, -(float)fi / 16.f);
        float ang = (float)s * freq;
        float sn, cs;
        sincosf(ang, &sn, &cs);
        qb[(size_t)row * 512 + i0]     = f2bs(x1 * cs - x2 * sn);
        qb[(size_t)row * 512 + i0 + 1] = f2bs(x1 * sn + x2 * cs);
    }
    if (tid < 64) {  // k RoPE: 64 pairs
        int i0 = tid * 2;
        int h = i0 >> 5;
        int fi = (i0 & 31) >> 1;
        float sc = hscale[16 + h];
        float x1 = sh[512 + i0] * sc, x2 = sh[512 + i0 + 1] * sc;
        float freq = powf(THETA_, -(float)fi / 16.f);
        float ang = (float)s * freq;
        float sn, cs;
        sincosf(ang, &sn, &cs);
        kb[(size_t)row * 128 + i0]     = f2bs(x1 * cs - x2 * sn);
        kb[(size_t)row * 128 + i0 + 1] = f2bs(x1 * sn + x2 * cs);
    }
}

// MFMA flash attention: merged heads (wave = head of KV group), k-range split
// into <=8-tile chunks, fixed-shift softmax => partials merge by pure addition
// into fp32 Onum/Lsum via atomicAdd. Grid (80 chunk-ids, 4 kvh, 4 b).
__global__ __launch_bounds__(256) void attn_mfma(
    const short* __restrict__ qb, const short* __restrict__ kb,
    const short* __restrict__ vtb, float* __restrict__ Onum,
    float* __restrict__ Lsum, const float* __restrict__ key_temp) {
    int idx = blockIdx.x, kvh = blockIdx.y, b = blockIdx.z;
    int qt, kt0, kt1;
    if (idx < 8)       { qt = idx;            kt0 = 0;     kt1 = qt + 1; }
    else if (idx < 24) { int j = idx - 8;  qt = 8  + (j >> 1); int t = j & 1;
                         kt0 = t * 8; kt1 = t ? qt + 1 : 8; }
    else if (idx < 48) { int j = idx - 24; qt = 16 + j / 3;    int t = j % 3;
                         kt0 = t * 8; kt1 = (t == 2) ? qt + 1 : t * 8 + 8; }
    else               { int j = idx - 48; qt = 24 + (j >> 2); int t = j & 3;
                         kt0 = t * 8; kt1 = (t == 3) ? qt + 1 : t * 8 + 8; }
    int s0 = qt * 64;
    int tid = threadIdx.x, wave = tid >> 6, lane = tid & 63;
    int cc = lane & 15, quad = lane >> 4;
    int h = kvh * 4 + wave;
    __shared__ short KF[2048];                      // K A-frags, 4KB
    __shared__ short VF[2048];                      // V B-frags, 4KB
    __shared__ __align__(16) short PF[4 * 64 * 72]; // per-wave P, 36KB
    short* PFw = PF + wave * 64 * 72;

    short8 qfrag[4];
#pragma unroll
    for (int qc = 0; qc < 4; ++qc)
        qfrag[qc] = *(const short8*)(qb +
            ((size_t)(b * S_LEN + s0 + qc * 16 + cc) * 512 + h * 32 + quad * 8));

    float4v accO[4][2] = {};
    float lpart[4] = {0.f, 0.f, 0.f, 0.f};
    float shift2 = -5.6568543f * key_temp[0] * LOG2E_;

    for (int kt = kt0; kt < kt1; ++kt) {
        __syncthreads();
        {
            int chunk = tid >> 6, q4 = (tid >> 4) & 3, c = tid & 15;
            const short* ksrc = kb +
                ((size_t)(b * S_LEN + kt * 64 + chunk * 16 + c) * 128 + kvh * 32 + q4 * 8);
            async_copy16(ksrc, KF + chunk * 512);
            int kc = tid >> 7, dc = (tid >> 6) & 1;
            const short* vsrc = vtb +
                ((size_t)((b * 4 + kvh) * 32 + dc * 16 + c) * S_LEN + kt * 64 + kc * 32 + q4 * 8);
            async_copy16(vsrc, VF + chunk * 512);
        }
        __syncthreads();

        // S^T = K·Q^T per (kchunk, qchunk): lane holds kpos=kchunk*16+quad*4+r, q=qchunk*16+cc
        float4v st[4][4];
#pragma unroll
        for (int kchunk = 0; kchunk < 4; ++kchunk) {
            short8 kfrag = *(const short8*)&KF[kchunk * 512 + lane * 8];
#pragma unroll
            for (int qc = 0; qc < 4; ++qc) {
                float4v z = (float4v){0.f, 0.f, 0.f, 0.f};
                st[kchunk][qc] = __builtin_amdgcn_mfma_f32_16x16x32_bf16(kfrag, qfrag[qc], z, 0, 0, 0);
            }
        }

        bool diag = (kt == qt);
#pragma unroll
        for (int kchunk = 0; kchunk < 4; ++kchunk)
#pragma unroll
            for (int qc = 0; qc < 4; ++qc) {
                float pv[4];
#pragma unroll
                for (int r = 0; r < 4; ++r) {
                    float e = exp2f(fmaf(st[kchunk][qc][r], LOG2E_, shift2));
                    if (diag) {
                        int krel = kchunk * 16 + quad * 4 + r;
                        int qrel = qc * 16 + cc;
                        e = (krel <= qrel) ? e : 0.f;
                    }
                    pv[r] = e;
                    lpart[qc] += e;
                }
                // pack 4 fp32 -> 4 bf16 (round-half-up) with 4 adds + 2 perms
                unsigned a0 = __float_as_uint(pv[0]) + 0x8000u;
                unsigned a1 = __float_as_uint(pv[1]) + 0x8000u;
                unsigned a2 = __float_as_uint(pv[2]) + 0x8000u;
                unsigned a3 = __float_as_uint(pv[3]) + 0x8000u;
                unsigned u0 = __builtin_amdgcn_perm(a1, a0, 0x07060302);
                unsigned u1 = __builtin_amdgcn_perm(a3, a2, 0x07060302);
                *(uint2*)&PFw[(qc * 16 + cc) * 72 + kchunk * 16 + quad * 4] = make_uint2(u0, u1);
            }

        short8 vf2[2][2];
#pragma unroll
        for (int kc = 0; kc < 2; ++kc)
#pragma unroll
            for (int dc = 0; dc < 2; ++dc)
                vf2[kc][dc] = *(const short8*)&VF[(kc * 2 + dc) * 512 + lane * 8];
#pragma unroll
        for (int qc = 0; qc < 4; ++qc)
#pragma unroll
            for (int kc = 0; kc < 2; ++kc) {
                short8 pfrag = *(const short8*)&PFw[(qc * 16 + cc) * 72 + kc * 32 + quad * 8];
                accO[qc][0] = __builtin_amdgcn_mfma_f32_16x16x32_bf16(pfrag, vf2[kc][0], accO[qc][0], 0, 0, 0);
                accO[qc][1] = __builtin_amdgcn_mfma_f32_16x16x32_bf16(pfrag, vf2[kc][1], accO[qc][1], 0, 0, 0);
            }
    }

    // epilogue: l reduce over quads, then atomic accumulate
#pragma unroll
    for (int qc = 0; qc < 4; ++qc) {
        lpart[qc] += __shfl_xor(lpart[qc], 16, 64);
        lpart[qc] += __shfl_xor(lpart[qc], 32, 64);
    }
    float lv = (quad == 0) ? lpart[0] : (quad == 1) ? lpart[1]
             : (quad == 2) ? lpart[2] : lpart[3];
    atomicAdd(&Lsum[((size_t)(b * S_LEN + s0 + quad * 16 + cc)) * 16 + h], lv);
#pragma unroll
    for (int qc = 0; qc < 4; ++qc)
#pragma unroll
        for (int r = 0; r < 4; ++r) {
            float* dst = Onum +
                ((size_t)(b * S_LEN + s0 + qc * 16 + quad * 4 + r) * 512 + h * 32 + cc);
            atomicAdd(dst + 0,  accO[qc][0][r]);
            atomicAdd(dst + 16, accO[qc][1][r]);
        }
}

// normalize by l, preout RMS, emit bf16 rows for the final MFMA GEMM
__global__ __launch_bounds__(256) void rms_preout_bf16(
    const float* __restrict__ Onum, const float* __restrict__ Lsum,
    const float* __restrict__ g, short* __restrict__ outb) {
    int row = blockIdx.x;
    const float* p = Onum + (size_t)row * 512;
    __shared__ float scratch[4];
    __shared__ float linv[16];
    int tid = threadIdx.x;
    if (tid < 16) linv[tid] = 1.f / Lsum[(size_t)row * 16 + tid];
    __syncthreads();
    float v0 = p[tid] * linv[tid >> 5];
    float v1 = p[tid + 256] * linv[(tid + 256) >> 5];
    float ssq = block_reduce_sum_256(v0 * v0 + v1 * v1, scratch);
    float r = rsqrtf(ssq / 512.f + EPS_);
    outb[(size_t)row * 512 + tid]       = f2bs(v0 * r * g[tid]);
    outb[(size_t)row * 512 + tid + 256] = f2bs(v1 * r * g[tid + 256]);
}

extern "C" void kernel_launch(void* const* d_in, const int* in_sizes, int n_in,
                              void* d_out, int out_size, void* d_ws, size_t ws_size,
                              hipStream_t stream) {
    (void)in_sizes; (void)n_in; (void)out_size; (void)ws_size;
    const float* x        = (const float*)d_in[0];
    const float* w_q      = (const float*)d_in[1];
    const float* w_k      = (const float*)d_in[2];
    const float* w_v      = (const float*)d_in[3];
    const float* g_latent = (const float*)d_in[4];
    const float* g_kv     = (const float*)d_in[5];
    const float* conv_q_w = (const float*)d_in[6];
    const float* conv_k_w = (const float*)d_in[7];
    const float* g_conv   = (const float*)d_in[8];
    const float* g_kconv  = (const float*)d_in[9];
    const float* g_postq  = (const float*)d_in[10];
    const float* g_postk  = (const float*)d_in[11];
    const float* key_temp = (const float*)d_in[12];
    const float* g_preout = (const float*)d_in[13];
    const float* w_o      = (const float*)d_in[14];
    float* out = (float*)d_out;

    char* ws = (char*)d_ws;
    const size_t R = NROWS;
    float* qkv   = (float*)ws;                        ws += R * 768 * 4;
    float* qmean = (float*)ws;                        ws += R * 32 * 4;
    float* kmean = (float*)ws;                        ws += R * 32 * 4;
    float* convq = (float*)ws;                        ws += R * 512 * 4;
    float* convk = (float*)ws;                        ws += R * 128 * 4;
    short* qbb   = (short*)ws;                        ws += R * 512 * 2;
    short* kbb   = (short*)ws;                        ws += R * 128 * 2;
    short* vtb   = (short*)ws;                        ws += R * 128 * 2;
    short* xb    = (short*)ws;                        ws += R * 2048 * 2;
    short* wqkvb = (short*)ws;                        ws += 768 * 2048 * 2;
    short* w_ob  = (short*)ws;                        ws += 2048 * 512 * 2;
    float* Lsum  = (float*)ws;                        ws += R * 16 * 4;
    // xb (32MB) is dead after the QKV GEMM: reuse front for attnb (8MB),
    // next 16MB for Onum.
    short* attnb = xb;
    float* Onum  = (float*)(xb + R * 512);

    dim3 blk(256);
    cvt_bf16<<<(NROWS * 2048) / 1024, blk, 0, stream>>>(x, xb, NROWS * 2048);
    cvt_bf16<<<(512 * 2048) / 1024, blk, 0, stream>>>(w_q, wqkvb, 512 * 2048);
    cvt_bf16<<<(128 * 2048) / 1024, blk, 0, stream>>>(w_k, wqkvb + 512 * 2048, 128 * 2048);
    cvt_bf16<<<(128 * 2048) / 1024, blk, 0, stream>>>(w_v, wqkvb + 640 * 2048, 128 * 2048);
    cvt_bf16<<<(2048 * 512) / 1024, blk, 0, stream>>>(w_o, w_ob, 2048 * 512);

    gemm_bf16_mfma<<<dim3(6, 64), blk, 0, stream>>>(xb, wqkvb, qkv, 768, 2048);
    rms_qkv_means<<<NROWS, blk, 0, stream>>>(qkv, g_latent, g_kv, qmean, kmean, vtb);
    causal_conv32<<<dim3(64, 16, 4), blk, 0, stream>>>(qkv, 768, 0, conv_q_w, convq, 512);
    causal_conv32<<<dim3(64, 4, 4), blk, 0, stream>>>(qkv, 768, 512, conv_k_w, convk, 128);
    mix_rows<<<NROWS, blk, 0, stream>>>(convq, convk, qmean, kmean, g_conv, g_kconv,
                                        g_postq, g_postk, key_temp, qbb, kbb);
    hipMemsetAsync(Onum, 0, R * 512 * 4, stream);
    hipMemsetAsync(Lsum, 0, R * 16 * 4, stream);
    attn_mfma<<<dim3(80, 4, 4), blk, 0, stream>>>(qbb, kbb, vtb, Onum, Lsum, key_temp);
    rms_preout_bf16<<<NROWS, blk, 0, stream>>>(Onum, Lsum, g_preout, attnb);
    gemm_bf16_mfma<<<dim3(16, 64), blk, 0, stream>>>(attnb, w_ob, out, 2048, 512);
}

// Round 6
// 400.345 us; speedup vs baseline: 6.0856x; 1.0581x over previous
//
#include <hip/hip_runtime.h>
#include <hip/hip_bf16.h>
#include <math.h>

constexpr int S_LEN = 2048;
constexpr int B_SZ  = 4;
constexpr int NROWS = B_SZ * S_LEN;   // 8192
constexpr float GAIN_  = 0.25f;
constexpr float EPS_   = 1e-6f;
constexpr float THETA_ = 10000.0f;
constexpr float SCALE_ = 0.17677669529663687f; // 1/sqrt(32)
constexpr float LOG2E_ = 1.44269504f;

typedef __attribute__((ext_vector_type(8))) short short8;
typedef __attribute__((ext_vector_type(4))) float float4v;

__device__ __forceinline__ short f2bs(float f) {
    __hip_bfloat16 h = __float2bfloat16(f);
    short r;
    __builtin_memcpy(&r, &h, 2);
    return r;
}

__device__ __forceinline__ void async_copy16(const short* g, short* l) {
    __builtin_amdgcn_global_load_lds(
        (const __attribute__((address_space(1))) void*)g,
        (__attribute__((address_space(3))) void*)l, 16, 0, 0);
}

__device__ __forceinline__ float block_reduce_sum_256(float v, float* scratch) {
    __syncthreads();
    for (int off = 32; off > 0; off >>= 1)
        v += __shfl_down(v, off, 64);
    int lane = threadIdx.x & 63;
    int wid  = threadIdx.x >> 6;
    if (lane == 0) scratch[wid] = v;
    __syncthreads();
    if (threadIdx.x == 0) scratch[0] = scratch[0] + scratch[1] + scratch[2] + scratch[3];
    __syncthreads();
    return scratch[0];
}

// fp32 -> bf16 cast, n % 4 == 0
__global__ __launch_bounds__(256) void cvt_bf16(
    const float* __restrict__ src, short* __restrict__ dst, int n) {
    int i = (blockIdx.x * 256 + threadIdx.x) * 4;
    if (i >= n) return;
    float4 v = *(const float4*)(src + i);
    dst[i + 0] = f2bs(v.x); dst[i + 1] = f2bs(v.y);
    dst[i + 2] = f2bs(v.z); dst[i + 3] = f2bs(v.w);
}

// all four weight casts in one launch: wq|wk|wv -> wqkvb (concat), wo -> wob
__global__ __launch_bounds__(256) void cvt_weights(
    const float* __restrict__ wq, const float* __restrict__ wk,
    const float* __restrict__ wv, const float* __restrict__ wo,
    short* __restrict__ wqkvb, short* __restrict__ wob) {
    int i = (blockIdx.x * 256 + threadIdx.x) * 4;
    const float* src;
    short* dst;
    int j;
    if (i < 1048576)      { src = wq; dst = wqkvb + i; j = i; }
    else if (i < 1310720) { src = wk; dst = wqkvb + i; j = i - 1048576; }
    else if (i < 1572864) { src = wv; dst = wqkvb + i; j = i - 1310720; }
    else                  { src = wo; dst = wob + (i - 1572864); j = i - 1572864; }
    float4 v = *(const float4*)(src + j);
    dst[0] = f2bs(v.x); dst[1] = f2bs(v.y);
    dst[2] = f2bs(v.z); dst[3] = f2bs(v.w);
}

// C[M x N] fp32 = A[M x K](bf16) @ B[N x K](bf16)^T.  M%128==0, N%128==0, K%32==0.
__global__ __launch_bounds__(256) void gemm_bf16_mfma(
    const short* __restrict__ A, const short* __restrict__ B,
    float* __restrict__ C, int N, int K) {
    __shared__ short As[128 * 32];
    __shared__ short Bs[128 * 32];
    int tid = threadIdx.x;
    int wave = tid >> 6, lane = tid & 63;
    int m0 = blockIdx.y * 128, n0 = blockIdx.x * 128;
    int wm = (wave >> 1) * 64, wn = (wave & 1) * 64;
    int mrow = lane & 15, quad = lane >> 4;
    float4v acc[4][4] = {};
    for (int k0 = 0; k0 < K; k0 += 32) {
        __syncthreads();
#pragma unroll
        for (int p = 0; p < 2; ++p) {
            int f = p * 256 + tid;
            int row = f >> 2, ch = (f & 3) * 8;
            const short* ga = A + (size_t)(m0 + row) * K + k0 + ch;
            const short* gb = B + (size_t)(n0 + row) * K + k0 + ch;
            async_copy16(ga, As + p * 2048 + wave * 512);
            async_copy16(gb, Bs + p * 2048 + wave * 512);
        }
        __syncthreads();
        short8 af[4], bf[4];
#pragma unroll
        for (int i = 0; i < 4; ++i)
            af[i] = *(const short8*)&As[(wm + i * 16 + mrow) * 32 + quad * 8];
#pragma unroll
        for (int j = 0; j < 4; ++j)
            bf[j] = *(const short8*)&Bs[(wn + j * 16 + mrow) * 32 + quad * 8];
#pragma unroll
        for (int i = 0; i < 4; ++i)
#pragma unroll
            for (int j = 0; j < 4; ++j)
                acc[i][j] = __builtin_amdgcn_mfma_f32_16x16x32_bf16(af[i], bf[j], acc[i][j], 0, 0, 0);
    }
#pragma unroll
    for (int i = 0; i < 4; ++i)
#pragma unroll
        for (int r = 0; r < 4; ++r) {
            int m = m0 + wm + i * 16 + quad * 4 + r;
            float* crow = C + (size_t)m * N + n0 + wn;
#pragma unroll
            for (int j = 0; j < 4; ++j)
                crow[j * 16 + mrow] = acc[i][j][r];
        }
}

// RMS of q (512, g_latent), k (128, g_kv), v (128, g_kv); q,k stored back to qkv,
// v stored as bf16 transposed vtb[(b*4+kvh)*32+d][s]. Also head-means of q and k.
__global__ __launch_bounds__(256) void rms_qkv_means(
    float* __restrict__ qkv, const float* __restrict__ g_latent,
    const float* __restrict__ g_kv,
    float* __restrict__ qmean, float* __restrict__ kmean,
    short* __restrict__ vtb) {
    int row = blockIdx.x;
    int b = row >> 11, s = row & (S_LEN - 1);
    float* p = qkv + (size_t)row * 768;
    __shared__ float sh[640];
    __shared__ float scratch[4];
    int tid = threadIdx.x;
    float v0 = p[tid], v1 = p[tid + 256], v2 = p[tid + 512];
    float ssq_q = block_reduce_sum_256(v0 * v0 + v1 * v1, scratch);
    float rq = rsqrtf(ssq_q / 512.f + EPS_);
    float q0 = v0 * rq * g_latent[tid];
    float q1 = v1 * rq * g_latent[tid + 256];
    p[tid] = q0; p[tid + 256] = q1;
    sh[tid] = q0; sh[tid + 256] = q1;
    float kpart = (tid < 128) ? v2 : 0.f;
    float vpart = (tid >= 128) ? v2 : 0.f;
    float ssq_k = block_reduce_sum_256(kpart * kpart, scratch);
    float ssq_v = block_reduce_sum_256(vpart * vpart, scratch);
    if (tid < 128) {
        float rk = rsqrtf(ssq_k / 128.f + EPS_);
        float kv = v2 * rk * g_kv[tid];
        p[512 + tid] = kv; sh[512 + tid] = kv;
    } else {
        float rv = rsqrtf(ssq_v / 128.f + EPS_);
        float vv = v2 * rv * g_kv[tid - 128];
        int d_full = tid - 128;
        vtb[((size_t)(b * 4 + (d_full >> 5)) * 32 + (d_full & 31)) * S_LEN + s] = f2bs(vv);
    }
    __syncthreads();
    if (tid < 32) {
        float sm = 0.f;
#pragma unroll
        for (int h = 0; h < 16; ++h) sm += sh[h * 32 + tid];
        qmean[(size_t)row * 32 + tid] = sm * (1.f / 16.f);
    } else if (tid < 64) {
        int d = tid - 32;
        float sm = 0.f;
#pragma unroll
        for (int h = 0; h < 4; ++h) sm += sh[512 + h * 32 + d];
        kmean[(size_t)row * 32 + d] = sm * 0.25f;
    }
}

// Grouped causal conv, 32 in / 32 out channels per group, K=3, left pad 2.
__global__ __launch_bounds__(256) void causal_conv32(
    const float* __restrict__ in, int ldin, int inoff,
    const float* __restrict__ w, float* __restrict__ out, int C) {
    int b = blockIdx.z, g = blockIdx.y, s0 = blockIdx.x * 32;
    __shared__ float wsh[32][3][32];   // [ic][tap][oc]
    __shared__ float ish[34][33];      // [pos][ic]
    int tid = threadIdx.x;
    for (int i = tid; i < 32 * 96; i += 256) {
        int oc = i / 96, r = i % 96;
        wsh[r / 3][r % 3][oc] = w[(size_t)(g * 32 + oc) * 96 + r];
    }
    for (int i = tid; i < 34 * 32; i += 256) {
        int pp = i >> 5, ic = i & 31;
        int s = s0 - 2 + pp;
        ish[pp][ic] = (s >= 0) ? in[((size_t)b * S_LEN + s) * ldin + inoff + g * 32 + ic] : 0.f;
    }
    __syncthreads();
    int sl = tid >> 3, oc0 = (tid & 7) * 4;
    float acc[4] = {0.f, 0.f, 0.f, 0.f};
    for (int ic = 0; ic < 32; ++ic) {
        float x0 = ish[sl][ic], x1 = ish[sl + 1][ic], x2 = ish[sl + 2][ic];
#pragma unroll
        for (int j = 0; j < 4; ++j)
            acc[j] += x0 * wsh[ic][0][oc0 + j] + x1 * wsh[ic][1][oc0 + j] + x2 * wsh[ic][2][oc0 + j];
    }
    float* orow = out + ((size_t)b * S_LEN + s0 + sl) * C + g * 32 + oc0;
    orow[0] = acc[0]; orow[1] = acc[1]; orow[2] = acc[2]; orow[3] = acc[3];
}

// Per-row: conv-RMS, + GAIN*mean-mix, post-RMS, per-head L2 norm, RoPE.
// Writes final q (512, pre-scaled by SCALE_) and k (128) as bf16.
__global__ __launch_bounds__(256) void mix_rows(
    const float* __restrict__ convq, const float* __restrict__ convk,
    const float* __restrict__ qmean, const float* __restrict__ kmean,
    const float* __restrict__ g_conv, const float* __restrict__ g_kconv,
    const float* __restrict__ g_postq, const float* __restrict__ g_postk,
    const float* __restrict__ key_temp,
    short* __restrict__ qb, short* __restrict__ kb) {
    int row = blockIdx.x;
    int s = row & (S_LEN - 1);
    int tid = threadIdx.x;
    __shared__ float sh[640];
    __shared__ float scratch[4];
    __shared__ float hscale[20];
    float q0 = convq[(size_t)row * 512 + tid];
    float q1 = convq[(size_t)row * 512 + tid + 256];
    float k0 = (tid < 128) ? convk[(size_t)row * 128 + tid] : 0.f;
    float ssq = block_reduce_sum_256(q0 * q0 + q1 * q1, scratch);
    float r1 = rsqrtf(ssq / 512.f + EPS_);
    float ssk = block_reduce_sum_256(k0 * k0, scratch);
    float rk1 = rsqrtf(ssk / 128.f + EPS_);
    float km = kmean[(size_t)row * 32 + (tid & 31)];
    float a0 = q0 * r1 * g_conv[tid] + GAIN_ * km;
    float a1 = q1 * r1 * g_conv[tid + 256] + GAIN_ * km;
    float ak = 0.f;
    if (tid < 128) ak = k0 * rk1 * g_kconv[tid] + GAIN_ * qmean[(size_t)row * 32 + (tid & 31)];
    float ssq2 = block_reduce_sum_256(a0 * a0 + a1 * a1, scratch);
    float r2 = rsqrtf(ssq2 / 512.f + EPS_);
    float ssk2 = block_reduce_sum_256(ak * ak, scratch);
    float rk2 = rsqrtf(ssk2 / 128.f + EPS_);
    sh[tid] = a0 * r2 * g_postq[tid];
    sh[tid + 256] = a1 * r2 * g_postq[tid + 256];
    if (tid < 128) sh[512 + tid] = ak * rk2 * g_postk[tid];
    __syncthreads();
    if (tid < 16) {
        float ssh = 0.f;
        for (int d = 0; d < 32; ++d) { float x = sh[tid * 32 + d]; ssh += x * x; }
        // sqrt(32) * SCALE_ == 1, SCALE_ folded into q
        hscale[tid] = 1.f / fmaxf(sqrtf(ssh), 1e-12f);
    } else if (tid < 20) {
        int h = tid - 16;
        float ssh = 0.f;
        for (int d = 0; d < 32; ++d) { float x = sh[512 + h * 32 + d]; ssh += x * x; }
        hscale[tid] = sqrtf(32.f) / fmaxf(sqrtf(ssh), 1e-12f) * key_temp[0];
    }
    __syncthreads();
    {   // q RoPE: 256 pairs
        int i0 = tid * 2;
        int h = i0 >> 5;
        int fi = (i0 & 31) >> 1;
        float sc = hscale[h];
        float x1 = sh[i0] * sc, x2 = sh[i0 + 1] * sc;
        float freq = powf(THETA_, -(float)fi / 16.f);
        float ang = (float)s * freq;
        float sn, cs;
        sincosf(ang, &sn, &cs);
        qb[(size_t)row * 512 + i0]     = f2bs(x1 * cs - x2 * sn);
        qb[(size_t)row * 512 + i0 + 1] = f2bs(x1 * sn + x2 * cs);
    }
    if (tid < 64) {  // k RoPE: 64 pairs
        int i0 = tid * 2;
        int h = i0 >> 5;
        int fi = (i0 & 31) >> 1;
        float sc = hscale[16 + h];
        float x1 = sh[512 + i0] * sc, x2 = sh[512 + i0 + 1] * sc;
        float freq = powf(THETA_, -(float)fi / 16.f);
        float ang = (float)s * freq;
        float sn, cs;
        sincosf(ang, &sn, &cs);
        kb[(size_t)row * 128 + i0]     = f2bs(x1 * cs - x2 * sn);
        kb[(size_t)row * 128 + i0 + 1] = f2bs(x1 * sn + x2 * cs);
    }
}

// MFMA flash attention, load-balanced by qt-pairing: block (pair,h,b) handles
// qt=pair and qt=31-pair sequentially => every block runs exactly 33 k-tile
// iters. Fixed-shift softmax (no max/rescale), direct O store (no atomics).
__global__ __launch_bounds__(256) void attn_mfma(
    const short* __restrict__ qb, const short* __restrict__ kb,
    const short* __restrict__ vtb, float* __restrict__ obuf,
    const float* __restrict__ key_temp) {
    int pair = blockIdx.x, h = blockIdx.y, b = blockIdx.z;
    int kvh = h >> 2;
    __shared__ short KF[2048];                      // K A-frags, 4KB
    __shared__ short VF[2048];                      // V B-frags, 4KB
    __shared__ __align__(16) short PF[4 * 16 * 72]; // per-wave P, 9KB
    int tid = threadIdx.x, wave = tid >> 6, lane = tid & 63;
    int cc = lane & 15, quad = lane >> 4;
    short* PFw = PF + wave * 16 * 72;
    float shift2 = -5.6568543f * key_temp[0] * LOG2E_;

    for (int half = 0; half < 2; ++half) {
        int qt = half ? (31 - pair) : pair;
        int s0 = qt * 64;
        short8 qfrag = *(const short8*)(qb +
            ((size_t)(b * S_LEN + s0 + wave * 16 + cc) * 512 + h * 32 + quad * 8));
        float4v accO[2];
        accO[0] = (float4v){0.f, 0.f, 0.f, 0.f};
        accO[1] = (float4v){0.f, 0.f, 0.f, 0.f};
        float lpart = 0.f;
        int qpos = s0 + wave * 16 + cc;

        for (int kt = 0; kt <= qt; ++kt) {
            __syncthreads();
            {
                int chunk = tid >> 6, q4 = (tid >> 4) & 3, c = tid & 15;
                const short* ksrc = kb +
                    ((size_t)(b * S_LEN + kt * 64 + chunk * 16 + c) * 128 + kvh * 32 + q4 * 8);
                async_copy16(ksrc, KF + chunk * 512);
                int kc = tid >> 7, dc = (tid >> 6) & 1;
                const short* vsrc = vtb +
                    ((size_t)((b * 4 + kvh) * 32 + dc * 16 + c) * S_LEN + kt * 64 + kc * 32 + q4 * 8);
                async_copy16(vsrc, VF + chunk * 512);
            }
            __syncthreads();

            // S^T = K·Q^T: lane holds kpos=chunk*16+quad*4+r, qcol=cc
            float4v st[4];
#pragma unroll
            for (int chunk = 0; chunk < 4; ++chunk) {
                short8 kfrag = *(const short8*)&KF[chunk * 512 + lane * 8];
                float4v z = (float4v){0.f, 0.f, 0.f, 0.f};
                st[chunk] = __builtin_amdgcn_mfma_f32_16x16x32_bf16(kfrag, qfrag, z, 0, 0, 0);
            }

            bool diag = (kt == qt);
#pragma unroll
            for (int chunk = 0; chunk < 4; ++chunk) {
                float pv[4];
#pragma unroll
                for (int r = 0; r < 4; ++r) {
                    float e = exp2f(fmaf(st[chunk][r], LOG2E_, shift2));
                    if (diag) {
                        int kpos = kt * 64 + chunk * 16 + quad * 4 + r;
                        e = (kpos <= qpos) ? e : 0.f;
                    }
                    pv[r] = e;
                    lpart += e;
                }
                // pack 4 fp32 -> 4 bf16 (round-half-up) with 4 adds + 2 perms
                unsigned a0 = __float_as_uint(pv[0]) + 0x8000u;
                unsigned a1 = __float_as_uint(pv[1]) + 0x8000u;
                unsigned a2 = __float_as_uint(pv[2]) + 0x8000u;
                unsigned a3 = __float_as_uint(pv[3]) + 0x8000u;
                unsigned u0 = __builtin_amdgcn_perm(a1, a0, 0x07060302);
                unsigned u1 = __builtin_amdgcn_perm(a3, a2, 0x07060302);
                *(uint2*)&PFw[cc * 72 + chunk * 16 + quad * 4] = make_uint2(u0, u1);
            }

            // PV: O[q][d] += P·V  (pfrag A[m=q][k], lane = q + 16*kquad)
#pragma unroll
            for (int kc = 0; kc < 2; ++kc) {
                short8 pfrag = *(const short8*)&PFw[cc * 72 + kc * 32 + quad * 8];
#pragma unroll
                for (int dc = 0; dc < 2; ++dc) {
                    short8 vfrag = *(const short8*)&VF[(kc * 2 + dc) * 512 + lane * 8];
                    accO[dc] = __builtin_amdgcn_mfma_f32_16x16x32_bf16(pfrag, vfrag, accO[dc], 0, 0, 0);
                }
            }
        }

        lpart += __shfl_xor(lpart, 16, 64);
        lpart += __shfl_xor(lpart, 32, 64);
#pragma unroll
        for (int r = 0; r < 4; ++r) {
            float linv = 1.f / __shfl(lpart, quad * 4 + r, 64);
            float* dst = obuf +
                ((size_t)(b * S_LEN + s0 + wave * 16 + quad * 4 + r) * 512 + h * 32 + cc);
            dst[0]  = accO[0][r] * linv;
            dst[16] = accO[1][r] * linv;
        }
    }
}

// preout RMS, emits bf16 rows for the final MFMA GEMM
__global__ __launch_bounds__(256) void rms_preout_bf16(
    const float* __restrict__ buf, const float* __restrict__ g,
    short* __restrict__ outb) {
    int row = blockIdx.x;
    const float* p = buf + (size_t)row * 512;
    __shared__ float scratch[4];
    int tid = threadIdx.x;
    float v0 = p[tid], v1 = p[tid + 256];
    float ssq = block_reduce_sum_256(v0 * v0 + v1 * v1, scratch);
    float r = rsqrtf(ssq / 512.f + EPS_);
    outb[(size_t)row * 512 + tid]       = f2bs(v0 * r * g[tid]);
    outb[(size_t)row * 512 + tid + 256] = f2bs(v1 * r * g[tid + 256]);
}

extern "C" void kernel_launch(void* const* d_in, const int* in_sizes, int n_in,
                              void* d_out, int out_size, void* d_ws, size_t ws_size,
                              hipStream_t stream) {
    (void)in_sizes; (void)n_in; (void)out_size; (void)ws_size;
    const float* x        = (const float*)d_in[0];
    const float* w_q      = (const float*)d_in[1];
    const float* w_k      = (const float*)d_in[2];
    const float* w_v      = (const float*)d_in[3];
    const float* g_latent = (const float*)d_in[4];
    const float* g_kv     = (const float*)d_in[5];
    const float* conv_q_w = (const float*)d_in[6];
    const float* conv_k_w = (const float*)d_in[7];
    const float* g_conv   = (const float*)d_in[8];
    const float* g_kconv  = (const float*)d_in[9];
    const float* g_postq  = (const float*)d_in[10];
    const float* g_postk  = (const float*)d_in[11];
    const float* key_temp = (const float*)d_in[12];
    const float* g_preout = (const float*)d_in[13];
    const float* w_o      = (const float*)d_in[14];
    float* out = (float*)d_out;

    char* ws = (char*)d_ws;
    const size_t R = NROWS;
    float* qkv   = (float*)ws;                        ws += R * 768 * 4;
    float* qmean = (float*)ws;                        ws += R * 32 * 4;
    float* kmean = (float*)ws;                        ws += R * 32 * 4;
    float* convq = (float*)ws;                        ws += R * 512 * 4;
    float* convk = (float*)ws;                        ws += R * 128 * 4;
    short* qbb   = (short*)ws;                        ws += R * 512 * 2;
    short* kbb   = (short*)ws;                        ws += R * 128 * 2;
    short* vtb   = (short*)ws;                        ws += R * 128 * 2;
    short* xb    = (short*)ws;                        ws += R * 2048 * 2;
    short* wqkvb = (short*)ws;                        ws += 768 * 2048 * 2;
    short* w_ob  = (short*)ws;                        ws += 2048 * 512 * 2;
    float* attn  = convq;          // convq consumed by mix_rows before attn writes
    short* attnb = xb;             // xb dead after QKV gemm

    dim3 blk(256);
    cvt_bf16<<<(NROWS * 2048) / 1024, blk, 0, stream>>>(x, xb, NROWS * 2048);
    cvt_weights<<<2560, blk, 0, stream>>>(w_q, w_k, w_v, w_o, wqkvb, w_ob);

    gemm_bf16_mfma<<<dim3(6, 64), blk, 0, stream>>>(xb, wqkvb, qkv, 768, 2048);
    rms_qkv_means<<<NROWS, blk, 0, stream>>>(qkv, g_latent, g_kv, qmean, kmean, vtb);
    causal_conv32<<<dim3(64, 16, 4), blk, 0, stream>>>(qkv, 768, 0, conv_q_w, convq, 512);
    causal_conv32<<<dim3(64, 4, 4), blk, 0, stream>>>(qkv, 768, 512, conv_k_w, convk, 128);
    mix_rows<<<NROWS, blk, 0, stream>>>(convq, convk, qmean, kmean, g_conv, g_kconv,
                                        g_postq, g_postk, key_temp, qbb, kbb);
    attn_mfma<<<dim3(16, 16, 4), blk, 0, stream>>>(qbb, kbb, vtb, attn, key_temp);
    rms_preout_bf16<<<NROWS, blk, 0, stream>>>(attn, g_preout, attnb);
    gemm_bf16_mfma<<<dim3(16, 64), blk, 0, stream>>>(attnb, w_ob, out, 2048, 512);
}

// Round 7
// 398.778 us; speedup vs baseline: 6.1095x; 1.0039x over previous
//
#include <hip/hip_runtime.h>
#include <hip/hip_bf16.h>
#include <math.h>

constexpr int S_LEN = 2048;
constexpr int B_SZ  = 4;
constexpr int NROWS = B_SZ * S_LEN;   // 8192
constexpr float GAIN_  = 0.25f;
constexpr float EPS_   = 1e-6f;
constexpr float THETA_ = 10000.0f;
constexpr float LOG2E_ = 1.44269504f;

typedef __attribute__((ext_vector_type(8))) short short8;
typedef __attribute__((ext_vector_type(4))) float float4v;

__device__ __forceinline__ short f2bs(float f) {
    __hip_bfloat16 h = __float2bfloat16(f);
    short r;
    __builtin_memcpy(&r, &h, 2);
    return r;
}

__device__ __forceinline__ void async_copy16(const short* g, short* l) {
    __builtin_amdgcn_global_load_lds(
        (const __attribute__((address_space(1))) void*)g,
        (__attribute__((address_space(3))) void*)l, 16, 0, 0);
}

__device__ __forceinline__ float block_reduce_sum_256(float v, float* scratch) {
    __syncthreads();
    for (int off = 32; off > 0; off >>= 1)
        v += __shfl_down(v, off, 64);
    int lane = threadIdx.x & 63;
    int wid  = threadIdx.x >> 6;
    if (lane == 0) scratch[wid] = v;
    __syncthreads();
    if (threadIdx.x == 0) scratch[0] = scratch[0] + scratch[1] + scratch[2] + scratch[3];
    __syncthreads();
    return scratch[0];
}

// fp32 -> bf16 cast, n % 4 == 0
__global__ __launch_bounds__(256) void cvt_bf16(
    const float* __restrict__ src, short* __restrict__ dst, int n) {
    int i = (blockIdx.x * 256 + threadIdx.x) * 4;
    if (i >= n) return;
    float4 v = *(const float4*)(src + i);
    dst[i + 0] = f2bs(v.x); dst[i + 1] = f2bs(v.y);
    dst[i + 2] = f2bs(v.z); dst[i + 3] = f2bs(v.w);
}

// all four weight casts in one launch: wq|wk|wv -> wqkvb (concat), wo -> wob
__global__ __launch_bounds__(256) void cvt_weights(
    const float* __restrict__ wq, const float* __restrict__ wk,
    const float* __restrict__ wv, const float* __restrict__ wo,
    short* __restrict__ wqkvb, short* __restrict__ wob) {
    int i = (blockIdx.x * 256 + threadIdx.x) * 4;
    const float* src;
    short* dst;
    int j;
    if (i < 1048576)      { src = wq; dst = wqkvb + i; j = i; }
    else if (i < 1310720) { src = wk; dst = wqkvb + i; j = i - 1048576; }
    else if (i < 1572864) { src = wv; dst = wqkvb + i; j = i - 1310720; }
    else                  { src = wo; dst = wob + (i - 1572864); j = i - 1572864; }
    float4 v = *(const float4*)(src + j);
    dst[0] = f2bs(v.x); dst[1] = f2bs(v.y);
    dst[2] = f2bs(v.z); dst[3] = f2bs(v.w);
}

// C[M x N] fp32 = A[M x K](bf16) @ B[N x K](bf16)^T.  M%128==0, N%128==0, K%32==0.
__global__ __launch_bounds__(256) void gemm_bf16_mfma(
    const short* __restrict__ A, const short* __restrict__ B,
    float* __restrict__ C, int N, int K) {
    __shared__ short As[128 * 32];
    __shared__ short Bs[128 * 32];
    int tid = threadIdx.x;
    int wave = tid >> 6, lane = tid & 63;
    int m0 = blockIdx.y * 128, n0 = blockIdx.x * 128;
    int wm = (wave >> 1) * 64, wn = (wave & 1) * 64;
    int mrow = lane & 15, quad = lane >> 4;
    float4v acc[4][4] = {};
    for (int k0 = 0; k0 < K; k0 += 32) {
        __syncthreads();
#pragma unroll
        for (int p = 0; p < 2; ++p) {
            int f = p * 256 + tid;
            int row = f >> 2, ch = (f & 3) * 8;
            const short* ga = A + (size_t)(m0 + row) * K + k0 + ch;
            const short* gb = B + (size_t)(n0 + row) * K + k0 + ch;
            async_copy16(ga, As + p * 2048 + wave * 512);
            async_copy16(gb, Bs + p * 2048 + wave * 512);
        }
        __syncthreads();
        short8 af[4], bf[4];
#pragma unroll
        for (int i = 0; i < 4; ++i)
            af[i] = *(const short8*)&As[(wm + i * 16 + mrow) * 32 + quad * 8];
#pragma unroll
        for (int j = 0; j < 4; ++j)
            bf[j] = *(const short8*)&Bs[(wn + j * 16 + mrow) * 32 + quad * 8];
#pragma unroll
        for (int i = 0; i < 4; ++i)
#pragma unroll
            for (int j = 0; j < 4; ++j)
                acc[i][j] = __builtin_amdgcn_mfma_f32_16x16x32_bf16(af[i], bf[j], acc[i][j], 0, 0, 0);
    }
#pragma unroll
    for (int i = 0; i < 4; ++i)
#pragma unroll
        for (int r = 0; r < 4; ++r) {
            int m = m0 + wm + i * 16 + quad * 4 + r;
            float* crow = C + (size_t)m * N + n0 + wn;
#pragma unroll
            for (int j = 0; j < 4; ++j)
                crow[j * 16 + mrow] = acc[i][j][r];
        }
}

// RMS of q (512, g_latent), k (128, g_kv), v (128, g_kv); q,k stored back to qkv,
// v stored as bf16 transposed vtb[(b*4+kvh)*32+d][s]. Also head-means of q and k.
__global__ __launch_bounds__(256) void rms_qkv_means(
    float* __restrict__ qkv, const float* __restrict__ g_latent,
    const float* __restrict__ g_kv,
    float* __restrict__ qmean, float* __restrict__ kmean,
    short* __restrict__ vtb) {
    int row = blockIdx.x;
    int b = row >> 11, s = row & (S_LEN - 1);
    float* p = qkv + (size_t)row * 768;
    __shared__ float sh[640];
    __shared__ float scratch[4];
    int tid = threadIdx.x;
    float v0 = p[tid], v1 = p[tid + 256], v2 = p[tid + 512];
    float ssq_q = block_reduce_sum_256(v0 * v0 + v1 * v1, scratch);
    float rq = rsqrtf(ssq_q / 512.f + EPS_);
    float q0 = v0 * rq * g_latent[tid];
    float q1 = v1 * rq * g_latent[tid + 256];
    p[tid] = q0; p[tid + 256] = q1;
    sh[tid] = q0; sh[tid + 256] = q1;
    float kpart = (tid < 128) ? v2 : 0.f;
    float vpart = (tid >= 128) ? v2 : 0.f;
    float ssq_k = block_reduce_sum_256(kpart * kpart, scratch);
    float ssq_v = block_reduce_sum_256(vpart * vpart, scratch);
    if (tid < 128) {
        float rk = rsqrtf(ssq_k / 128.f + EPS_);
        float kv = v2 * rk * g_kv[tid];
        p[512 + tid] = kv; sh[512 + tid] = kv;
    } else {
        float rv = rsqrtf(ssq_v / 128.f + EPS_);
        float vv = v2 * rv * g_kv[tid - 128];
        int d_full = tid - 128;
        vtb[((size_t)(b * 4 + (d_full >> 5)) * 32 + (d_full & 31)) * S_LEN + s] = f2bs(vv);
    }
    __syncthreads();
    if (tid < 32) {
        float sm = 0.f;
#pragma unroll
        for (int h = 0; h < 16; ++h) sm += sh[h * 32 + tid];
        qmean[(size_t)row * 32 + tid] = sm * (1.f / 16.f);
    } else if (tid < 64) {
        int d = tid - 32;
        float sm = 0.f;
#pragma unroll
        for (int h = 0; h < 4; ++h) sm += sh[512 + h * 32 + d];
        kmean[(size_t)row * 32 + d] = sm * 0.25f;
    }
}

// Grouped causal conv, 32 in / 32 out channels per group, K=3, left pad 2.
__global__ __launch_bounds__(256) void causal_conv32(
    const float* __restrict__ in, int ldin, int inoff,
    const float* __restrict__ w, float* __restrict__ out, int C) {
    int b = blockIdx.z, g = blockIdx.y, s0 = blockIdx.x * 32;
    __shared__ float wsh[32][3][32];   // [ic][tap][oc]
    __shared__ float ish[34][33];      // [pos][ic]
    int tid = threadIdx.x;
    for (int i = tid; i < 32 * 96; i += 256) {
        int oc = i / 96, r = i % 96;
        wsh[r / 3][r % 3][oc] = w[(size_t)(g * 32 + oc) * 96 + r];
    }
    for (int i = tid; i < 34 * 32; i += 256) {
        int pp = i >> 5, ic = i & 31;
        int s = s0 - 2 + pp;
        ish[pp][ic] = (s >= 0) ? in[((size_t)b * S_LEN + s) * ldin + inoff + g * 32 + ic] : 0.f;
    }
    __syncthreads();
    int sl = tid >> 3, oc0 = (tid & 7) * 4;
    float acc[4] = {0.f, 0.f, 0.f, 0.f};
    for (int ic = 0; ic < 32; ++ic) {
        float x0 = ish[sl][ic], x1 = ish[sl + 1][ic], x2 = ish[sl + 2][ic];
#pragma unroll
        for (int j = 0; j < 4; ++j)
            acc[j] += x0 * wsh[ic][0][oc0 + j] + x1 * wsh[ic][1][oc0 + j] + x2 * wsh[ic][2][oc0 + j];
    }
    float* orow = out + ((size_t)b * S_LEN + s0 + sl) * C + g * 32 + oc0;
    orow[0] = acc[0]; orow[1] = acc[1]; orow[2] = acc[2]; orow[3] = acc[3];
}

// Per-row: conv-RMS, + GAIN*mean-mix, post-RMS, per-head L2 norm, RoPE.
// Writes final q (512, pre-scaled by SCALE_) and k (128) as bf16.
__global__ __launch_bounds__(256) void mix_rows(
    const float* __restrict__ convq, const float* __restrict__ convk,
    const float* __restrict__ qmean, const float* __restrict__ kmean,
    const float* __restrict__ g_conv, const float* __restrict__ g_kconv,
    const float* __restrict__ g_postq, const float* __restrict__ g_postk,
    const float* __restrict__ key_temp,
    short* __restrict__ qb, short* __restrict__ kb) {
    int row = blockIdx.x;
    int s = row & (S_LEN - 1);
    int tid = threadIdx.x;
    __shared__ float sh[640];
    __shared__ float scratch[4];
    __shared__ float hscale[20];
    float q0 = convq[(size_t)row * 512 + tid];
    float q1 = convq[(size_t)row * 512 + tid + 256];
    float k0 = (tid < 128) ? convk[(size_t)row * 128 + tid] : 0.f;
    float ssq = block_reduce_sum_256(q0 * q0 + q1 * q1, scratch);
    float r1 = rsqrtf(ssq / 512.f + EPS_);
    float ssk = block_reduce_sum_256(k0 * k0, scratch);
    float rk1 = rsqrtf(ssk / 128.f + EPS_);
    float km = kmean[(size_t)row * 32 + (tid & 31)];
    float a0 = q0 * r1 * g_conv[tid] + GAIN_ * km;
    float a1 = q1 * r1 * g_conv[tid + 256] + GAIN_ * km;
    float ak = 0.f;
    if (tid < 128) ak = k0 * rk1 * g_kconv[tid] + GAIN_ * qmean[(size_t)row * 32 + (tid & 31)];
    float ssq2 = block_reduce_sum_256(a0 * a0 + a1 * a1, scratch);
    float r2 = rsqrtf(ssq2 / 512.f + EPS_);
    float ssk2 = block_reduce_sum_256(ak * ak, scratch);
    float rk2 = rsqrtf(ssk2 / 128.f + EPS_);
    sh[tid] = a0 * r2 * g_postq[tid];
    sh[tid + 256] = a1 * r2 * g_postq[tid + 256];
    if (tid < 128) sh[512 + tid] = ak * rk2 * g_postk[tid];
    __syncthreads();
    if (tid < 16) {
        float ssh = 0.f;
        for (int d = 0; d < 32; ++d) { float x = sh[tid * 32 + d]; ssh += x * x; }
        // sqrt(32) * (1/sqrt(32)) == 1: attention scale folded into q
        hscale[tid] = 1.f / fmaxf(sqrtf(ssh), 1e-12f);
    } else if (tid < 20) {
        int h = tid - 16;
        float ssh = 0.f;
        for (int d = 0; d < 32; ++d) { float x = sh[512 + h * 32 + d]; ssh += x * x; }
        hscale[tid] = sqrtf(32.f) / fmaxf(sqrtf(ssh), 1e-12f) * key_temp[0];
    }
    __syncthreads();
    {   // q RoPE: 256 pairs
        int i0 = tid * 2;
        int h = i0 >> 5;
        int fi = (i0 & 31) >> 1;
        float sc = hscale[h];
        float x1 = sh[i0] * sc, x2 = sh[i0 + 1] * sc;
        float freq = powf(THETA_, -(float)fi / 16.f);
        float ang = (float)s * freq;
        float sn, cs;
        sincosf(ang, &sn, &cs);
        qb[(size_t)row * 512 + i0]     = f2bs(x1 * cs - x2 * sn);
        qb[(size_t)row * 512 + i0 + 1] = f2bs(x1 * sn + x2 * cs);
    }
    if (tid < 64) {  // k RoPE: 64 pairs
        int i0 = tid * 2;
        int h = i0 >> 5;
        int fi = (i0 & 31) >> 1;
        float sc = hscale[16 + h];
        float x1 = sh[512 + i0] * sc, x2 = sh[512 + i0 + 1] * sc;
        float freq = powf(THETA_, -(float)fi / 16.f);
        float ang = (float)s * freq;
        float sn, cs;
        sincosf(ang, &sn, &cs);
        kb[(size_t)row * 128 + i0]     = f2bs(x1 * cs - x2 * sn);
        kb[(size_t)row * 128 + i0 + 1] = f2bs(x1 * sn + x2 * cs);
    }
}

// MFMA flash attention: qt-paired (balanced) AND k-parity split (2x parallelism).
// Block (pair*2+parity, h, b) does qt=pair and qt=31-pair, kt stepping by 2 from
// parity. Fixed-shift softmax => parity partials merge by addition; each parity
// writes its own fp32 O-numerator / l-sum (no atomics, no memset needed).
__global__ __launch_bounds__(256) void attn_mfma(
    const short* __restrict__ qb, const short* __restrict__ kb,
    const short* __restrict__ vtb, float* __restrict__ OnumA,
    float* __restrict__ OnumB, float* __restrict__ LsumA,
    float* __restrict__ LsumB, const float* __restrict__ key_temp) {
    int pp = blockIdx.x, h = blockIdx.y, b = blockIdx.z;
    int pair = pp >> 1, parity = pp & 1;
    int kvh = h >> 2;
    float* __restrict__ Onum = parity ? OnumB : OnumA;
    float* __restrict__ Lsum = parity ? LsumB : LsumA;
    __shared__ short KF[2048];                      // K A-frags, 4KB
    __shared__ short VF[2048];                      // V B-frags, 4KB
    __shared__ __align__(16) short PF[4 * 16 * 72]; // per-wave P, 9KB
    int tid = threadIdx.x, wave = tid >> 6, lane = tid & 63;
    int cc = lane & 15, quad = lane >> 4;
    short* PFw = PF + wave * 16 * 72;
    float shift2 = -5.6568543f * key_temp[0] * LOG2E_;

    // per-lane staging pointers (advance by 2 k-tiles per iter)
    const short* ksrc0 = kb +
        ((size_t)(b * S_LEN + parity * 64 + (tid >> 6) * 16 + (tid & 15)) * 128
         + kvh * 32 + ((tid >> 4) & 3) * 8);
    const short* vsrc0 = vtb +
        ((size_t)((b * 4 + kvh) * 32 + ((tid >> 6) & 1) * 16 + (tid & 15)) * S_LEN
         + parity * 64 + (tid >> 7) * 32 + ((tid >> 4) & 3) * 8);

    for (int half = 0; half < 2; ++half) {
        int qt = half ? (31 - pair) : pair;
        int s0 = qt * 64;
        short8 qfrag = *(const short8*)(qb +
            ((size_t)(b * S_LEN + s0 + wave * 16 + cc) * 512 + h * 32 + quad * 8));
        float4v accO[2];
        accO[0] = (float4v){0.f, 0.f, 0.f, 0.f};
        accO[1] = (float4v){0.f, 0.f, 0.f, 0.f};
        float lpart = 0.f;
        int qpos = s0 + wave * 16 + cc;
        const short* ksrc = ksrc0;
        const short* vsrc = vsrc0;

        for (int kt = parity; kt <= qt; kt += 2) {
            __syncthreads();
            async_copy16(ksrc, KF + (tid >> 6) * 512);
            async_copy16(vsrc, VF + (tid >> 6) * 512);
            ksrc += 2 * 64 * 128;
            vsrc += 2 * 64;
            __syncthreads();

            // S^T = K·Q^T: lane holds kpos=chunk*16+quad*4+r, qcol=cc
            float4v st[4];
#pragma unroll
            for (int chunk = 0; chunk < 4; ++chunk) {
                short8 kfrag = *(const short8*)&KF[chunk * 512 + lane * 8];
                float4v z = (float4v){0.f, 0.f, 0.f, 0.f};
                st[chunk] = __builtin_amdgcn_mfma_f32_16x16x32_bf16(kfrag, qfrag, z, 0, 0, 0);
            }

            bool diag = (kt == qt);
#pragma unroll
            for (int chunk = 0; chunk < 4; ++chunk) {
                float pv[4];
#pragma unroll
                for (int r = 0; r < 4; ++r) {
                    float e = exp2f(fmaf(st[chunk][r], LOG2E_, shift2));
                    if (diag) {
                        int kpos = kt * 64 + chunk * 16 + quad * 4 + r;
                        e = (kpos <= qpos) ? e : 0.f;
                    }
                    pv[r] = e;
                    lpart += e;
                }
                // pack 4 fp32 -> 4 bf16 (round-half-up) with 4 adds + 2 perms
                unsigned a0 = __float_as_uint(pv[0]) + 0x8000u;
                unsigned a1 = __float_as_uint(pv[1]) + 0x8000u;
                unsigned a2 = __float_as_uint(pv[2]) + 0x8000u;
                unsigned a3 = __float_as_uint(pv[3]) + 0x8000u;
                unsigned u0 = __builtin_amdgcn_perm(a1, a0, 0x07060302);
                unsigned u1 = __builtin_amdgcn_perm(a3, a2, 0x07060302);
                *(uint2*)&PFw[cc * 72 + chunk * 16 + quad * 4] = make_uint2(u0, u1);
            }

            // PV: O[q][d] += P·V  (pfrag A[m=q][k], lane = q + 16*kquad)
#pragma unroll
            for (int kc = 0; kc < 2; ++kc) {
                short8 pfrag = *(const short8*)&PFw[cc * 72 + kc * 32 + quad * 8];
#pragma unroll
                for (int dc = 0; dc < 2; ++dc) {
                    short8 vfrag = *(const short8*)&VF[(kc * 2 + dc) * 512 + lane * 8];
                    accO[dc] = __builtin_amdgcn_mfma_f32_16x16x32_bf16(pfrag, vfrag, accO[dc], 0, 0, 0);
                }
            }
        }

        // partial epilogue: no divide, plain stores to this parity's buffers
        lpart += __shfl_xor(lpart, 16, 64);
        lpart += __shfl_xor(lpart, 32, 64);
        if (quad == 0)
            Lsum[((size_t)(b * S_LEN + s0 + wave * 16 + cc)) * 16 + h] = lpart;
#pragma unroll
        for (int r = 0; r < 4; ++r) {
            float* dst = Onum +
                ((size_t)(b * S_LEN + s0 + wave * 16 + quad * 4 + r) * 512 + h * 32 + cc);
            dst[0]  = accO[0][r];
            dst[16] = accO[1][r];
        }
    }
}

// merge parity partials, divide by l, preout RMS, emit bf16 rows
__global__ __launch_bounds__(256) void rms_preout_bf16(
    const float* __restrict__ OA, const float* __restrict__ OB,
    const float* __restrict__ LA, const float* __restrict__ LB,
    const float* __restrict__ g, short* __restrict__ outb) {
    int row = blockIdx.x;
    __shared__ float scratch[4];
    __shared__ float linv[16];
    int tid = threadIdx.x;
    if (tid < 16)
        linv[tid] = 1.f / (LA[(size_t)row * 16 + tid] + LB[(size_t)row * 16 + tid]);
    __syncthreads();
    float v0 = (OA[(size_t)row * 512 + tid] + OB[(size_t)row * 512 + tid]) * linv[tid >> 5];
    float v1 = (OA[(size_t)row * 512 + tid + 256] + OB[(size_t)row * 512 + tid + 256])
               * linv[(tid + 256) >> 5];
    float ssq = block_reduce_sum_256(v0 * v0 + v1 * v1, scratch);
    float r = rsqrtf(ssq / 512.f + EPS_);
    outb[(size_t)row * 512 + tid]       = f2bs(v0 * r * g[tid]);
    outb[(size_t)row * 512 + tid + 256] = f2bs(v1 * r * g[tid + 256]);
}

extern "C" void kernel_launch(void* const* d_in, const int* in_sizes, int n_in,
                              void* d_out, int out_size, void* d_ws, size_t ws_size,
                              hipStream_t stream) {
    (void)in_sizes; (void)n_in; (void)out_size; (void)ws_size;
    const float* x        = (const float*)d_in[0];
    const float* w_q      = (const float*)d_in[1];
    const float* w_k      = (const float*)d_in[2];
    const float* w_v      = (const float*)d_in[3];
    const float* g_latent = (const float*)d_in[4];
    const float* g_kv     = (const float*)d_in[5];
    const float* conv_q_w = (const float*)d_in[6];
    const float* conv_k_w = (const float*)d_in[7];
    const float* g_conv   = (const float*)d_in[8];
    const float* g_kconv  = (const float*)d_in[9];
    const float* g_postq  = (const float*)d_in[10];
    const float* g_postk  = (const float*)d_in[11];
    const float* key_temp = (const float*)d_in[12];
    const float* g_preout = (const float*)d_in[13];
    const float* w_o      = (const float*)d_in[14];
    float* out = (float*)d_out;

    char* ws = (char*)d_ws;
    const size_t R = NROWS;
    float* qkv   = (float*)ws;                        ws += R * 768 * 4;
    float* qmean = (float*)ws;                        ws += R * 32 * 4;
    float* kmean = (float*)ws;                        ws += R * 32 * 4;
    float* convq = (float*)ws;                        ws += R * 512 * 4;
    float* convk = (float*)ws;                        ws += R * 128 * 4;
    short* qbb   = (short*)ws;                        ws += R * 512 * 2;
    short* kbb   = (short*)ws;                        ws += R * 128 * 2;
    short* vtb   = (short*)ws;                        ws += R * 128 * 2;
    short* xb    = (short*)ws;                        ws += R * 2048 * 2;
    short* wqkvb = (short*)ws;                        ws += 768 * 2048 * 2;
    short* w_ob  = (short*)ws;                        ws += 2048 * 512 * 2;
    // overlays (all dead by the time attn runs):
    float* OnumA = convq;          // 16MB, convq consumed by mix_rows
    float* OnumB = qkv;            // 16MB of 25MB, qkv consumed by convs
    float* LsumA = qmean;          // 0.5MB of 1MB, consumed by mix_rows
    float* LsumB = kmean;
    short* attnb = xb;             // xb dead after QKV gemm

    dim3 blk(256);
    cvt_bf16<<<(NROWS * 2048) / 1024, blk, 0, stream>>>(x, xb, NROWS * 2048);
    cvt_weights<<<2560, blk, 0, stream>>>(w_q, w_k, w_v, w_o, wqkvb, w_ob);

    gemm_bf16_mfma<<<dim3(6, 64), blk, 0, stream>>>(xb, wqkvb, qkv, 768, 2048);
    rms_qkv_means<<<NROWS, blk, 0, stream>>>(qkv, g_latent, g_kv, qmean, kmean, vtb);
    causal_conv32<<<dim3(64, 16, 4), blk, 0, stream>>>(qkv, 768, 0, conv_q_w, convq, 512);
    causal_conv32<<<dim3(64, 4, 4), blk, 0, stream>>>(qkv, 768, 512, conv_k_w, convk, 128);
    mix_rows<<<NROWS, blk, 0, stream>>>(convq, convk, qmean, kmean, g_conv, g_kconv,
                                        g_postq, g_postk, key_temp, qbb, kbb);
    attn_mfma<<<dim3(32, 16, 4), blk, 0, stream>>>(qbb, kbb, vtb, OnumA, OnumB,
                                                   LsumA, LsumB, key_temp);
    rms_preout_bf16<<<NROWS, blk, 0, stream>>>(OnumA, OnumB, LsumA, LsumB,
                                               g_preout, attnb);
    gemm_bf16_mfma<<<dim3(16, 64), blk, 0, stream>>>(attnb, w_ob, out, 2048, 512);
}